// Round 11
// baseline (580.925 us; speedup 1.0000x reference)
//
#include <hip/hip_runtime.h>
#include <math.h>

// Problem constants
#define BB 4
#define SS 64
#define NN 256
#define FF 32
#define HH 64
#define MM (BB*SS)      // 256 graphs
#define NSEQ (BB*NN)    // 1024 sequences
#define TT SS           // 64 timesteps
#define MROWS (NSEQ*TT) // 65536 GEMM rows

// fast activations: v_rcp_f32 (~1ulp) instead of IEEE divide
__device__ __forceinline__ float fast_rcp(float x) { return __builtin_amdgcn_rcpf(x); }
__device__ __forceinline__ float sigmoid_f(float x) { return fast_rcp(1.0f + __expf(-x)); }
__device__ __forceinline__ float tanh_f(float x) {
    float t = __expf(-2.0f * fabsf(x));
    float r = (1.0f - t) * fast_rcp(1.0f + t);
    return copysignf(r, x);
}

// LDS-only barrier: waits ONLY lgkmcnt (LDS) before s_barrier, leaving global
// prefetch loads / stores IN FLIGHT across the barrier (the __syncthreads()
// drain of vmcnt(0) was serially exposing HBM latency every LSTM step).
// sched_barrier(0) pins post-barrier ds_reads (guide rule #18).
__device__ __forceinline__ void lds_barrier() {
    asm volatile("s_waitcnt lgkmcnt(0)" ::: "memory");
    __builtin_amdgcn_s_barrier();
    __builtin_amdgcn_sched_barrier(0);
}

// ---- bf16 split helpers (RTNE hi, hi+lo captures ~17 mantissa bits) ----
typedef __bf16 bf16x8 __attribute__((ext_vector_type(8)));
typedef float  f32x4  __attribute__((ext_vector_type(4)));

__device__ __forceinline__ __bf16 bfh(float x) {
    unsigned u = __float_as_uint(x);
    unsigned r = (u + 0x7FFFu + ((u >> 16) & 1u)) >> 16;
    return __builtin_bit_cast(__bf16, (unsigned short)r);
}
__device__ __forceinline__ float bf2f(__bf16 b) {
    unsigned u = ((unsigned)__builtin_bit_cast(unsigned short, b)) << 16;
    return __uint_as_float(u);
}

// ---------------------------------------------------------------------------
// GAT layer v2 (unchanged): one block per graph (256 blocks, 256 threads).
// ---------------------------------------------------------------------------
template<int FIN>
__global__ __launch_bounds__(256) void gat_kernel(
    const float* __restrict__ xin,   // [M][N][FIN]
    const float* __restrict__ adj,   // [M][N][N]
    const float* __restrict__ W,     // [FIN][64]
    const float* __restrict__ a,     // [128]
    const float* __restrict__ gamma_, const float* __restrict__ beta_,
    float* __restrict__ gout)        // [M][N][64]
{
    constexpr int HP = 68;
    constexpr int KC = 32;
    constexpr int PP = 260;
    __shared__ __align__(16) float h_lds[256 * HP];
    __shared__ __align__(16) float p_s[2][KC * PP];
    __shared__ float s1[256], s2[256], srow[256];

    const int m = blockIdx.x;
    const int tid = threadIdx.x;
    const int c = tid & 63;
    const int w = tid >> 6;

    {
        float wreg[FIN];
#pragma unroll
        for (int f = 0; f < FIN; ++f) wreg[f] = W[f * 64 + c];
        const float* xm = xin + (size_t)m * NN * FIN;
        for (int i0 = 0; i0 < 64; ++i0) {
            int i = (i0 << 2) | w;
            float acc = 0.0f;
#pragma unroll
            for (int f4 = 0; f4 < FIN / 4; ++f4) {
                float4 xv = *(const float4*)&xm[i * FIN + f4 * 4];
                acc += xv.x * wreg[f4*4] + xv.y * wreg[f4*4+1]
                     + xv.z * wreg[f4*4+2] + xv.w * wreg[f4*4+3];
            }
            h_lds[i * HP + c] = acc;
        }
    }
    __syncthreads();

    {
        float acc1 = 0.0f, acc2 = 0.0f;
        const float* hr = &h_lds[tid * HP];
#pragma unroll
        for (int c4 = 0; c4 < 16; ++c4) {
            float4 hv  = *(const float4*)&hr[c4 * 4];
            float4 av1 = *(const float4*)&a[c4 * 4];
            float4 av2 = *(const float4*)&a[64 + c4 * 4];
            acc1 += hv.x * av1.x + hv.y * av1.y + hv.z * av1.z + hv.w * av1.w;
            acc2 += hv.x * av2.x + hv.y * av2.y + hv.z * av2.z + hv.w * av2.w;
        }
        s1[tid] = acc1; s2[tid] = acc2;
    }
    __syncthreads();

    const float* adjr = adj + ((size_t)m * NN + tid) * NN;
    const int ty = tid >> 3;
    const int tx = tid & 7;
    const float s1v = s1[tid];

    float4 areg[8];
    float srow_acc = 0.0f;
    float acc[8][8];
#pragma unroll
    for (int r = 0; r < 8; ++r)
#pragma unroll
        for (int q = 0; q < 8; ++q) acc[r][q] = 0.0f;

    auto load_chunk = [&](int ch) {
#pragma unroll
        for (int q = 0; q < 8; ++q)
            areg[q] = *(const float4*)&adjr[ch * KC + q * 4];
    };
    auto make_p = [&](int ch, int buf) {
        float s2r[KC];
#pragma unroll
        for (int q = 0; q < 8; ++q) {
            float4 sv = *(const float4*)&s2[ch * KC + q * 4];
            s2r[q*4+0] = sv.x; s2r[q*4+1] = sv.y; s2r[q*4+2] = sv.z; s2r[q*4+3] = sv.w;
        }
        const float* af = (const float*)areg;
#pragma unroll
        for (int kk = 0; kk < KC; ++kk) {
            float e = s1v + s2r[kk];
            e = (e > 0.0f) ? e : 0.2f * e;
            float p = (af[kk] > 0.0f) ? __expf(e) : 0.0f;
            srow_acc += p;
            p_s[buf][kk * PP + tid] = p;
        }
    };

    load_chunk(0);
    make_p(0, 0);
    __syncthreads();

    for (int ch = 0; ch < 8; ++ch) {
        if (ch < 7) load_chunk(ch + 1);
        {
            const float* pb = p_s[ch & 1];
            const int jb = ch * KC;
#pragma unroll 4
            for (int kk = 0; kk < KC; ++kk) {
                const float* pk = &pb[kk * PP + ty * 8];
                float4 p0 = *(const float4*)pk;
                float4 p1 = *(const float4*)(pk + 4);
                const float* hk = &h_lds[(jb + kk) * HP + tx * 8];
                float4 h0 = *(const float4*)hk;
                float4 h1 = *(const float4*)(hk + 4);
                float pv[8] = {p0.x,p0.y,p0.z,p0.w, p1.x,p1.y,p1.z,p1.w};
                float hv[8] = {h0.x,h0.y,h0.z,h0.w, h1.x,h1.y,h1.z,h1.w};
#pragma unroll
                for (int r = 0; r < 8; ++r)
#pragma unroll
                    for (int q = 0; q < 8; ++q)
                        acc[r][q] += pv[r] * hv[q];
            }
        }
        if (ch < 7) make_p(ch + 1, (ch + 1) & 1);
        else        srow[tid] = srow_acc;
        __syncthreads();
    }

    const int i0 = ty * 8;
    float4 sr0 = *(const float4*)&srow[i0];
    float4 sr1 = *(const float4*)&srow[i0 + 4];
    float rinv[8] = {1.0f/sr0.x, 1.0f/sr0.y, 1.0f/sr0.z, 1.0f/sr0.w,
                     1.0f/sr1.x, 1.0f/sr1.y, 1.0f/sr1.z, 1.0f/sr1.w};
    float4 gm0 = *(const float4*)&gamma_[tx * 8];
    float4 gm1 = *(const float4*)&gamma_[tx * 8 + 4];
    float4 bt0 = *(const float4*)&beta_[tx * 8];
    float4 bt1 = *(const float4*)&beta_[tx * 8 + 4];
    float gm[8] = {gm0.x,gm0.y,gm0.z,gm0.w, gm1.x,gm1.y,gm1.z,gm1.w};
    float bt[8] = {bt0.x,bt0.y,bt0.z,bt0.w, bt1.x,bt1.y,bt1.z,bt1.w};

#pragma unroll
    for (int r = 0; r < 8; ++r) {
        float v[8];
        float sm = 0.0f, sq = 0.0f;
#pragma unroll
        for (int q = 0; q < 8; ++q) {
            v[q] = acc[r][q] * rinv[r];
            sm += v[q]; sq += v[q] * v[q];
        }
#pragma unroll
        for (int off = 1; off < 8; off <<= 1) {
            sm += __shfl_xor(sm, off);
            sq += __shfl_xor(sq, off);
        }
        float mu  = sm * (1.0f / 64.0f);
        float var = sq * (1.0f / 64.0f) - mu * mu;
        float rs  = rsqrtf(var + 1e-5f);
        float o[8];
#pragma unroll
        for (int q = 0; q < 8; ++q) {
            float hn = (v[q] - mu) * rs * gm[q] + bt[q];
            o[q] = (hn > 0.0f) ? hn : (__expf(hn) - 1.0f);
        }
        float* gp = &gout[((size_t)m * NN + i0 + r) * 64 + tx * 8];
        *(float4*)gp       = make_float4(o[0], o[1], o[2], o[3]);
        *(float4*)(gp + 4) = make_float4(o[4], o[5], o[6], o[7]);
    }
}

// ---------------------------------------------------------------------------
// residual + gate*g, reshaped to sequence layout [B*N][T][H] (unchanged)
// ---------------------------------------------------------------------------
__global__ __launch_bounds__(256) void combine_kernel(
    const float* __restrict__ x,      // [B*S*N][32]
    const float* __restrict__ g1,     // [B*S*N][64]
    const float* __restrict__ res_W,  // [32][64]
    const float* __restrict__ res_b,  // [64]
    const float* __restrict__ alpha_p,
    float* __restrict__ seqout)       // [B*N][T][64]
{
    int row = blockIdx.x * 4 + (threadIdx.x >> 6);
    int h = threadIdx.x & 63;
    int mg = row >> 8, n = row & 255;
    int b = mg >> 6, s = mg & 63;
    const float* xr = x + (size_t)row * 32;
    float acc = res_b[h];
#pragma unroll
    for (int f4 = 0; f4 < 8; ++f4) {
        float4 xv = *(const float4*)&xr[f4 * 4];
        acc += xv.x * res_W[(f4*4    ) * 64 + h] + xv.y * res_W[(f4*4 + 1) * 64 + h]
             + xv.z * res_W[(f4*4 + 2) * 64 + h] + xv.w * res_W[(f4*4 + 3) * 64 + h];
    }
    float alpha = fminf(fmaxf(alpha_p[0], 0.0f), 1.0f);
    acc += alpha * g1[(size_t)row * 64 + h];
    seqout[(((size_t)(b * NN + n)) * TT + s) * 64 + h] = acc;
}

// ---------------------------------------------------------------------------
// W pre-convert: Wih[2][K][256] fp32 -> fragment-ordered bf16 hi/lo.
// idx = ((dir*NKC + kc)*16 + ng)*512 + g*128 + nl*8 + j
//   holds W[dir][kc*32 + 8*g + j][ng*16 + nl].
// ---------------------------------------------------------------------------
template<int K>
__global__ __launch_bounds__(256) void wcvt_kernel(
    const float* __restrict__ Wih, __bf16* __restrict__ Wh, __bf16* __restrict__ Wl)
{
    constexpr int NKC = K / 32;
    int idx = blockIdx.x * 256 + threadIdx.x;
    int j   = idx & 7;
    int nl  = (idx >> 3) & 15;
    int g   = (idx >> 7) & 3;
    int ng  = (idx >> 9) & 15;
    int rest = idx >> 13;                 // dir*NKC + kc
    int kc  = rest & (NKC - 1);
    int dir = rest / NKC;
    int k = kc * 32 + g * 8 + j;
    int n = ng * 16 + nl;
    float x = Wih[((size_t)dir * K + k) * 256 + n];
    __bf16 h = bfh(x);
    Wh[idx] = h;
    Wl[idx] = bfh(x - bf2f(h));
}

// ---------------------------------------------------------------------------
// Whh pre-convert (both layers, one launch): same frag layout as wcvt<64>.
// out: [layer][hi 32768 | lo 32768] bf16.
// ---------------------------------------------------------------------------
__global__ __launch_bounds__(256) void whhcvt_kernel(
    const float* __restrict__ W0, const float* __restrict__ W1,
    __bf16* __restrict__ outw)
{
    int idx = blockIdx.x * 256 + threadIdx.x;   // 0..65535
    int lay = idx >> 15;
    int r   = idx & 32767;
    int j   = r & 7;
    int nl  = (r >> 3) & 15;
    int g   = (r >> 7) & 3;
    int ng  = (r >> 9) & 15;
    int rest = r >> 13;                  // dir*2 + kc
    int kc  = rest & 1;
    int dir = rest >> 1;
    int k = kc * 32 + g * 8 + j;
    int n = ng * 16 + nl;
    const float* W = lay ? W1 : W0;
    float x = W[((size_t)dir * 64 + k) * 256 + n];
    __bf16 h = bfh(x);
    outw[lay * 65536 + r]         = h;
    outw[lay * 65536 + 32768 + r] = bfh(x - bf2f(h));
}

// ---------------------------------------------------------------------------
// xg GEMM via split-bf16 MFMA — GATE-GROUPED wave columns + coalesced float4
// epilogue into [k][gate] (colp) layout (unchanged from r10).
// ---------------------------------------------------------------------------
template<int K>
__global__ __launch_bounds__(256, 2) void xg_mfma_kernel(
    const float* __restrict__ A,       // [MROWS][K]
    const __bf16* __restrict__ Wh,     // frag-ordered
    const __bf16* __restrict__ Wl,
    const float* __restrict__ bih,     // [2][256]
    const float* __restrict__ bhh,     // [2][256]
    float* __restrict__ xg)            // [2][MROWS][64k][4g]
{
    constexpr int NKC = K / 32;
    __shared__ __bf16 a_h[2][128 * 32];
    __shared__ __bf16 a_l[2][128 * 32];

    const int tid  = threadIdx.x;
    const int lane = tid & 63;
    const int w    = tid >> 6;
    const int wr   = w >> 1, wc = w & 1;

    int bid = blockIdx.x;
    int wg  = (bid >> 3) | ((bid & 7) << 8);
    int cd  = wg & 3;
    int m0  = (wg >> 2) * 128;
    int dir = cd >> 1;
    const int kq = (cd & 1) * 2 + wc;    // wave's 16-k group (0..3)

    f32x4 acc[4][4];
#pragma unroll
    for (int mi = 0; mi < 4; ++mi)
#pragma unroll
        for (int ni = 0; ni < 4; ++ni)
            acc[mi][ni] = (f32x4){0.0f, 0.0f, 0.0f, 0.0f};

    const int srow = tid >> 1;
    const int g0   = (tid & 1) * 2;
    const float* abase = A + (size_t)(m0 + srow) * K + (tid & 1) * 16;
    const int soff0 = srow * 32 + (( g0      ^ (srow & 3)) * 8);
    const int soff1 = srow * 32 + (((g0 + 1) ^ (srow & 3)) * 8);

    int aoff[4];
#pragma unroll
    for (int mi = 0; mi < 4; ++mi)
        aoff[mi] = (wr * 64 + mi * 16 + (lane & 15)) * 32
                 + (((lane >> 4) ^ (lane & 3)) * 8);

    auto cvtstore = [&](const float* f, int buf) {
        bf16x8 h0, h1, l0, l1;
#pragma unroll
        for (int i = 0; i < 8; ++i) {
            __bf16 ha = bfh(f[i]);
            __bf16 hb = bfh(f[8 + i]);
            h0[i] = ha; l0[i] = bfh(f[i]     - bf2f(ha));
            h1[i] = hb; l1[i] = bfh(f[8 + i] - bf2f(hb));
        }
        *(bf16x8*)&a_h[buf][soff0] = h0;
        *(bf16x8*)&a_h[buf][soff1] = h1;
        *(bf16x8*)&a_l[buf][soff0] = l0;
        *(bf16x8*)&a_l[buf][soff1] = l1;
    };

    {
        float f[16];
#pragma unroll
        for (int i = 0; i < 4; ++i) {
            float4 v = *(const float4*)(abase + i * 4);
            f[i*4+0] = v.x; f[i*4+1] = v.y; f[i*4+2] = v.z; f[i*4+3] = v.w;
        }
        cvtstore(f, 0);
    }
    __syncthreads();

    int buf = 0;
    for (int kc = 0; kc < NKC; ++kc) {
        float f[16];
        if (kc + 1 < NKC) {
#pragma unroll
            for (int i = 0; i < 4; ++i) {
                float4 v = *(const float4*)(abase + (kc + 1) * 32 + i * 4);
                f[i*4+0] = v.x; f[i*4+1] = v.y; f[i*4+2] = v.z; f[i*4+3] = v.w;
            }
        }
        bf16x8 bh[4], bl[4];
#pragma unroll
        for (int ni = 0; ni < 4; ++ni) {   // ni = gate
            size_t fb = ((size_t)((dir * NKC + kc) * 16 + ni * 4 + kq)) * 512 + lane * 8;
            bh[ni] = *(const bf16x8*)(Wh + fb);
            bl[ni] = *(const bf16x8*)(Wl + fb);
        }
        bf16x8 ah[4], al[4];
#pragma unroll
        for (int mi = 0; mi < 4; ++mi) {
            ah[mi] = *(const bf16x8*)&a_h[buf][aoff[mi]];
            al[mi] = *(const bf16x8*)&a_l[buf][aoff[mi]];
        }
#pragma unroll
        for (int mi = 0; mi < 4; ++mi)
#pragma unroll
            for (int ni = 0; ni < 4; ++ni)
                acc[mi][ni] = __builtin_amdgcn_mfma_f32_16x16x32_bf16(
                    ah[mi], bh[ni], acc[mi][ni], 0, 0, 0);
#pragma unroll
        for (int mi = 0; mi < 4; ++mi)
#pragma unroll
            for (int ni = 0; ni < 4; ++ni)
                acc[mi][ni] = __builtin_amdgcn_mfma_f32_16x16x32_bf16(
                    al[mi], bh[ni], acc[mi][ni], 0, 0, 0);
#pragma unroll
        for (int mi = 0; mi < 4; ++mi)
#pragma unroll
            for (int ni = 0; ni < 4; ++ni)
                acc[mi][ni] = __builtin_amdgcn_mfma_f32_16x16x32_bf16(
                    ah[mi], bl[ni], acc[mi][ni], 0, 0, 0);

        if (kc + 1 < NKC) cvtstore(f, buf ^ 1);
        __syncthreads();
        buf ^= 1;
    }

    // epilogue: assemble i,f,g,o per (row,k) into one coalesced float4
    const int kcol = kq * 16 + (lane & 15);
    float bias4[4];
#pragma unroll
    for (int g = 0; g < 4; ++g)
        bias4[g] = bih[dir * 256 + g * 64 + kcol] + bhh[dir * 256 + g * 64 + kcol];
#pragma unroll
    for (int mi = 0; mi < 4; ++mi) {
        int mrow = m0 + wr * 64 + mi * 16 + ((lane >> 4) << 2);
#pragma unroll
        for (int r = 0; r < 4; ++r) {
            float4 v = make_float4(acc[mi][0][r] + bias4[0], acc[mi][1][r] + bias4[1],
                                   acc[mi][2][r] + bias4[2], acc[mi][3][r] + bias4[3]);
            *(float4*)&xg[((size_t)dir * MROWS + mrow + r) * 256 + kcol * 4] = v;
        }
    }
}

// ---------------------------------------------------------------------------
// LSTM recurrence v9 = v8 (G=4, grid 512, 2 blocks/CU) with LDS-ONLY barrier:
// __syncthreads() drained vmcnt(0) each step, serially exposing the xg
// prefetch's HBM latency (r10: MfmaUtil+VALU = 70%, ~1000cy/step stall).
// lds_barrier() waits lgkmcnt only -> global loads stay in flight across
// the barrier; their completion is enforced at the USE point (next step).
// ---------------------------------------------------------------------------
__global__ __launch_bounds__(256, 2) void lstm_rec_kernel(
    const float* __restrict__ xg,     // [2][NSEQ][T][64k][4g]
    const __bf16* __restrict__ whhf,  // [hi 32768 | lo 32768] frag-ordered
    float* __restrict__ out,
    int write_all)
{
    const int tid  = threadIdx.x;
    const int wv   = tid >> 6;        // wave 0..3 = k-slice
    const int lane = tid & 63;
    const int nl   = lane & 15;
    const int lq   = lane >> 4;

    const int bid  = blockIdx.x;      // grid 512
    const int dir  = bid & 1;
    const int seq0 = (bid >> 1) * 4;  // 4 seqs per block

    // B fragments: Whh' hi/lo, held in VGPRs for the whole kernel
    const __bf16* wh = whhf;
    const __bf16* wl = whhf + 32768;
    bf16x8 bh[2][4], bl[2][4];
#pragma unroll
    for (int kc = 0; kc < 2; ++kc)
#pragma unroll
        for (int g = 0; g < 4; ++g) {
            size_t fb = ((size_t)((dir * 2 + kc) * 16 + g * 4 + wv)) * 512 + lane * 8;
            bh[kc][g] = *(const bf16x8*)(wh + fb);
            bl[kc][g] = *(const bf16x8*)(wl + fb);
        }

    // h broadcast buffers: [parity][s(16)][k(64)] bf16, XOR-swizzled on k>>3
    __shared__ __align__(16) __bf16 h_hi[2048];
    __shared__ __align__(16) __bf16 h_lo[2048];
    {
        uint4 z = {0, 0, 0, 0};
        *(uint4*)&h_hi[tid * 8] = z;
        *(uint4*)&h_lo[tid * 8] = z;
    }

    const int k   = wv * 16 + nl;     // this lane's hidden index (cell phase)
    const int g8k = k >> 3;

    float c[4] = {0.0f, 0.0f, 0.0f, 0.0f};
    float4 xc[4] = {}, xn[4] = {};

    // stepping pointers
    const float* pxg = xg + (((size_t)dir * NSEQ + seq0) * TT
                             + (dir ? (TT - 1) : 0)) * 256 + k * 4;
    const int dstep = dir ? -256 : 256;
    float* pout = out + ((size_t)seq0 * TT + (dir ? (TT - 1) : 0)) * 128
                + dir * 64 + k;
    const int ostep = dir ? -128 : 128;

    auto load_xg = [&](float4 (&d)[4]) {
        if (lane < 16) {
#pragma unroll
            for (int r = 0; r < 4; ++r)
                d[r] = *(const float4*)(pxg + (size_t)r * TT * 256);
        }
        pxg += dstep;
    };

    load_xg(xc);
    lds_barrier();

    int buf = 0;
    for (int step = 0; step < TT; ++step) {
        // A fragments: h(step) from LDS buf
        const int aof0 = buf * 1024 + nl * 64 + (((0 + lq) ^ (nl & 7)) * 8);
        const int aof1 = buf * 1024 + nl * 64 + (((4 + lq) ^ (nl & 7)) * 8);
        bf16x8 ah0 = *(const bf16x8*)&h_hi[aof0];
        bf16x8 ah1 = *(const bf16x8*)&h_hi[aof1];
        bf16x8 al0 = *(const bf16x8*)&h_lo[aof0];
        bf16x8 al1 = *(const bf16x8*)&h_lo[aof1];

        if (step + 1 < TT) load_xg(xn);   // prefetch next t (stays in flight)

        f32x4 acc[4];
#pragma unroll
        for (int g = 0; g < 4; ++g) acc[g] = (f32x4){0.0f, 0.0f, 0.0f, 0.0f};
#pragma unroll
        for (int g = 0; g < 4; ++g)
            acc[g] = __builtin_amdgcn_mfma_f32_16x16x32_bf16(ah0, bh[0][g], acc[g], 0, 0, 0);
#pragma unroll
        for (int g = 0; g < 4; ++g)
            acc[g] = __builtin_amdgcn_mfma_f32_16x16x32_bf16(ah1, bh[1][g], acc[g], 0, 0, 0);
#pragma unroll
        for (int g = 0; g < 4; ++g)
            acc[g] = __builtin_amdgcn_mfma_f32_16x16x32_bf16(al0, bh[0][g], acc[g], 0, 0, 0);
#pragma unroll
        for (int g = 0; g < 4; ++g)
            acc[g] = __builtin_amdgcn_mfma_f32_16x16x32_bf16(al1, bh[1][g], acc[g], 0, 0, 0);
#pragma unroll
        for (int g = 0; g < 4; ++g)
            acc[g] = __builtin_amdgcn_mfma_f32_16x16x32_bf16(ah0, bl[0][g], acc[g], 0, 0, 0);
#pragma unroll
        for (int g = 0; g < 4; ++g)
            acc[g] = __builtin_amdgcn_mfma_f32_16x16x32_bf16(ah1, bl[1][g], acc[g], 0, 0, 0);

        if (lane < 16) {
            // seqs 0..3 in acc rows 0..3 (lq==0 lanes)
#pragma unroll
            for (int r = 0; r < 4; ++r) {
                float iv = sigmoid_f(acc[0][r] + xc[r].x);
                float fv = sigmoid_f(acc[1][r] + xc[r].y);
                float gv = tanh_f  (acc[2][r] + xc[r].z);
                float ov = sigmoid_f(acc[3][r] + xc[r].w);
                c[r] = fv * c[r] + iv * gv;
                float h = ov * tanh_f(c[r]);
                int off = (buf ^ 1) * 1024 + r * 64 + ((g8k ^ r) * 8) + (k & 7);
                __bf16 hh = bfh(h);
                h_hi[off] = hh;
                h_lo[off] = bfh(h - bf2f(hh));
                if (write_all)
                    pout[(size_t)r * TT * 128] = h;
                else if (step == TT - 1)
                    out[(size_t)(seq0 + r) * 128 + dir * 64 + k] = h;
            }
        }
        pout += ostep;
        lds_barrier();
        buf ^= 1;
#pragma unroll
        for (int r = 0; r < 4; ++r) xc[r] = xn[r];
    }
}

// ---------------------------------------------------------------------------
__global__ __launch_bounds__(256) void fc_kernel(
    const float* __restrict__ fin,   // [NSEQ][128]
    const float* __restrict__ fc_W,  // [128]
    const float* __restrict__ fc_b,  // [1]
    float* __restrict__ outp)        // [NSEQ]
{
    int s = blockIdx.x * 256 + threadIdx.x;
    const float* fr = fin + (size_t)s * 128;
    float acc = fc_b[0];
#pragma unroll
    for (int k4 = 0; k4 < 32; ++k4) {
        float4 fv = *(const float4*)&fr[k4 * 4];
        float4 wv2 = *(const float4*)&fc_W[k4 * 4];
        acc += fv.x * wv2.x + fv.y * wv2.y + fv.z * wv2.z + fv.w * wv2.w;
    }
    outp[s] = acc;
}

// ---------------------------------------------------------------------------
extern "C" void kernel_launch(void* const* d_in, const int* in_sizes, int n_in,
                              void* d_out, int out_size, void* d_ws, size_t ws_size,
                              hipStream_t stream) {
    const float* x       = (const float*)d_in[0];
    const float* adj     = (const float*)d_in[1];
    const float* gat0_W  = (const float*)d_in[2];
    const float* gat0_a  = (const float*)d_in[3];
    const float* gat0_g  = (const float*)d_in[4];
    const float* gat0_b  = (const float*)d_in[5];
    const float* gat1_W  = (const float*)d_in[6];
    const float* gat1_a  = (const float*)d_in[7];
    const float* gat1_g  = (const float*)d_in[8];
    const float* gat1_b  = (const float*)d_in[9];
    const float* res_W   = (const float*)d_in[10];
    const float* res_b   = (const float*)d_in[11];
    const float* alpha_g = (const float*)d_in[12];
    const float* l0_Wih  = (const float*)d_in[13];
    const float* l0_Whh  = (const float*)d_in[14];
    const float* l0_bih  = (const float*)d_in[15];
    const float* l0_bhh  = (const float*)d_in[16];
    const float* l1_Wih  = (const float*)d_in[17];
    const float* l1_Whh  = (const float*)d_in[18];
    const float* l1_bih  = (const float*)d_in[19];
    const float* l1_bhh  = (const float*)d_in[20];
    const float* fc_W    = (const float*)d_in[21];
    const float* fc_b    = (const float*)d_in[22];

    float* ws = (float*)d_ws;
    float* g0    = ws;                    // [M][N][64]
    float* g1    = ws + 4194304;          // [M][N][64]
    float* seq   = ws + 8388608;          // [B*N][T][64]
    float* xg    = ws + 12582912;         // [2][65536][256]
    float* fin   = ws + 46137344;         // [NSEQ][128]
    float* o1    = ws;                    // reuse g0+g1 [NSEQ][T][128]

    // Wih' (bf16 hi/lo, frag-ordered) OVERLAPS fin: lifetimes disjoint
    __bf16* w0h = (__bf16*)(ws + 46137344);
    __bf16* w0l = w0h + 2 * 64 * 256;
    __bf16* w1h = w0l + 2 * 64 * 256;
    __bf16* w1l = w1h + 2 * 128 * 256;

    // Whh' frags live in the seq region (dead after xg_mfma<64>)
    __bf16* whhf = (__bf16*)seq;          // [2 layers][hi 32768 | lo 32768]

    wcvt_kernel<64><<<128, 256, 0, stream>>>(l0_Wih, w0h, w0l);
    wcvt_kernel<128><<<256, 256, 0, stream>>>(l1_Wih, w1h, w1l);
    gat_kernel<32><<<MM, 256, 0, stream>>>(x, adj, gat0_W, gat0_a, gat0_g, gat0_b, g0);
    gat_kernel<64><<<MM, 256, 0, stream>>>(g0, adj, gat1_W, gat1_a, gat1_g, gat1_b, g1);
    combine_kernel<<<(BB*SS*NN)/4, 256, 0, stream>>>(x, g1, res_W, res_b, alpha_g, seq);
    xg_mfma_kernel<64><<<2048, 256, 0, stream>>>(seq, w0h, w0l, l0_bih, l0_bhh, xg);
    whhcvt_kernel<<<256, 256, 0, stream>>>(l0_Whh, l1_Whh, whhf);
    lstm_rec_kernel<<<512, 256, 0, stream>>>(xg, whhf, o1, 1);
    xg_mfma_kernel<128><<<2048, 256, 0, stream>>>(o1, w1h, w1l, l1_bih, l1_bhh, xg);
    lstm_rec_kernel<<<512, 256, 0, stream>>>(xg, whhf + 65536, fin, 0);
    fc_kernel<<<NSEQ/256, 256, 0, stream>>>(fin, fc_W, fc_b, (float*)d_out);
}

// Round 12
// 562.054 us; speedup vs baseline: 1.0336x; 1.0336x over previous
//
#include <hip/hip_runtime.h>
#include <math.h>

// Problem constants
#define BB 4
#define SS 64
#define NN 256
#define FF 32
#define HH 64
#define MM (BB*SS)      // 256 graphs
#define NSEQ (BB*NN)    // 1024 sequences
#define TT SS           // 64 timesteps
#define MROWS (NSEQ*TT) // 65536 GEMM rows

// fast activations: v_rcp_f32 (~1ulp) instead of IEEE divide
__device__ __forceinline__ float fast_rcp(float x) { return __builtin_amdgcn_rcpf(x); }
__device__ __forceinline__ float sigmoid_f(float x) { return fast_rcp(1.0f + __expf(-x)); }
__device__ __forceinline__ float tanh_f(float x) {
    float t = __expf(-2.0f * fabsf(x));
    float r = (1.0f - t) * fast_rcp(1.0f + t);
    return copysignf(r, x);
}

// LDS-only barrier: waits ONLY lgkmcnt (LDS) before s_barrier, leaving global
// prefetch loads / stores IN FLIGHT across the barrier.
// sched_barrier(0) pins post-barrier ds_reads (guide rule #18).
__device__ __forceinline__ void lds_barrier() {
    asm volatile("s_waitcnt lgkmcnt(0)" ::: "memory");
    __builtin_amdgcn_s_barrier();
    __builtin_amdgcn_sched_barrier(0);
}

// ---- bf16 split helpers (RTNE hi, hi+lo captures ~17 mantissa bits) ----
typedef __bf16 bf16x8 __attribute__((ext_vector_type(8)));
typedef float  f32x4  __attribute__((ext_vector_type(4)));

__device__ __forceinline__ __bf16 bfh(float x) {
    unsigned u = __float_as_uint(x);
    unsigned r = (u + 0x7FFFu + ((u >> 16) & 1u)) >> 16;
    return __builtin_bit_cast(__bf16, (unsigned short)r);
}
__device__ __forceinline__ float bf2f(__bf16 b) {
    unsigned u = ((unsigned)__builtin_bit_cast(unsigned short, b)) << 16;
    return __uint_as_float(u);
}

// ---------------------------------------------------------------------------
// GAT layer v2 (unchanged): one block per graph (256 blocks, 256 threads).
// ---------------------------------------------------------------------------
template<int FIN>
__global__ __launch_bounds__(256) void gat_kernel(
    const float* __restrict__ xin,   // [M][N][FIN]
    const float* __restrict__ adj,   // [M][N][N]
    const float* __restrict__ W,     // [FIN][64]
    const float* __restrict__ a,     // [128]
    const float* __restrict__ gamma_, const float* __restrict__ beta_,
    float* __restrict__ gout)        // [M][N][64]
{
    constexpr int HP = 68;
    constexpr int KC = 32;
    constexpr int PP = 260;
    __shared__ __align__(16) float h_lds[256 * HP];
    __shared__ __align__(16) float p_s[2][KC * PP];
    __shared__ float s1[256], s2[256], srow[256];

    const int m = blockIdx.x;
    const int tid = threadIdx.x;
    const int c = tid & 63;
    const int w = tid >> 6;

    {
        float wreg[FIN];
#pragma unroll
        for (int f = 0; f < FIN; ++f) wreg[f] = W[f * 64 + c];
        const float* xm = xin + (size_t)m * NN * FIN;
        for (int i0 = 0; i0 < 64; ++i0) {
            int i = (i0 << 2) | w;
            float acc = 0.0f;
#pragma unroll
            for (int f4 = 0; f4 < FIN / 4; ++f4) {
                float4 xv = *(const float4*)&xm[i * FIN + f4 * 4];
                acc += xv.x * wreg[f4*4] + xv.y * wreg[f4*4+1]
                     + xv.z * wreg[f4*4+2] + xv.w * wreg[f4*4+3];
            }
            h_lds[i * HP + c] = acc;
        }
    }
    __syncthreads();

    {
        float acc1 = 0.0f, acc2 = 0.0f;
        const float* hr = &h_lds[tid * HP];
#pragma unroll
        for (int c4 = 0; c4 < 16; ++c4) {
            float4 hv  = *(const float4*)&hr[c4 * 4];
            float4 av1 = *(const float4*)&a[c4 * 4];
            float4 av2 = *(const float4*)&a[64 + c4 * 4];
            acc1 += hv.x * av1.x + hv.y * av1.y + hv.z * av1.z + hv.w * av1.w;
            acc2 += hv.x * av2.x + hv.y * av2.y + hv.z * av2.z + hv.w * av2.w;
        }
        s1[tid] = acc1; s2[tid] = acc2;
    }
    __syncthreads();

    const float* adjr = adj + ((size_t)m * NN + tid) * NN;
    const int ty = tid >> 3;
    const int tx = tid & 7;
    const float s1v = s1[tid];

    float4 areg[8];
    float srow_acc = 0.0f;
    float acc[8][8];
#pragma unroll
    for (int r = 0; r < 8; ++r)
#pragma unroll
        for (int q = 0; q < 8; ++q) acc[r][q] = 0.0f;

    auto load_chunk = [&](int ch) {
#pragma unroll
        for (int q = 0; q < 8; ++q)
            areg[q] = *(const float4*)&adjr[ch * KC + q * 4];
    };
    auto make_p = [&](int ch, int buf) {
        float s2r[KC];
#pragma unroll
        for (int q = 0; q < 8; ++q) {
            float4 sv = *(const float4*)&s2[ch * KC + q * 4];
            s2r[q*4+0] = sv.x; s2r[q*4+1] = sv.y; s2r[q*4+2] = sv.z; s2r[q*4+3] = sv.w;
        }
        const float* af = (const float*)areg;
#pragma unroll
        for (int kk = 0; kk < KC; ++kk) {
            float e = s1v + s2r[kk];
            e = (e > 0.0f) ? e : 0.2f * e;
            float p = (af[kk] > 0.0f) ? __expf(e) : 0.0f;
            srow_acc += p;
            p_s[buf][kk * PP + tid] = p;
        }
    };

    load_chunk(0);
    make_p(0, 0);
    __syncthreads();

    for (int ch = 0; ch < 8; ++ch) {
        if (ch < 7) load_chunk(ch + 1);
        {
            const float* pb = p_s[ch & 1];
            const int jb = ch * KC;
#pragma unroll 4
            for (int kk = 0; kk < KC; ++kk) {
                const float* pk = &pb[kk * PP + ty * 8];
                float4 p0 = *(const float4*)pk;
                float4 p1 = *(const float4*)(pk + 4);
                const float* hk = &h_lds[(jb + kk) * HP + tx * 8];
                float4 h0 = *(const float4*)hk;
                float4 h1 = *(const float4*)(hk + 4);
                float pv[8] = {p0.x,p0.y,p0.z,p0.w, p1.x,p1.y,p1.z,p1.w};
                float hv[8] = {h0.x,h0.y,h0.z,h0.w, h1.x,h1.y,h1.z,h1.w};
#pragma unroll
                for (int r = 0; r < 8; ++r)
#pragma unroll
                    for (int q = 0; q < 8; ++q)
                        acc[r][q] += pv[r] * hv[q];
            }
        }
        if (ch < 7) make_p(ch + 1, (ch + 1) & 1);
        else        srow[tid] = srow_acc;
        __syncthreads();
    }

    const int i0 = ty * 8;
    float4 sr0 = *(const float4*)&srow[i0];
    float4 sr1 = *(const float4*)&srow[i0 + 4];
    float rinv[8] = {1.0f/sr0.x, 1.0f/sr0.y, 1.0f/sr0.z, 1.0f/sr0.w,
                     1.0f/sr1.x, 1.0f/sr1.y, 1.0f/sr1.z, 1.0f/sr1.w};
    float4 gm0 = *(const float4*)&gamma_[tx * 8];
    float4 gm1 = *(const float4*)&gamma_[tx * 8 + 4];
    float4 bt0 = *(const float4*)&beta_[tx * 8];
    float4 bt1 = *(const float4*)&beta_[tx * 8 + 4];
    float gm[8] = {gm0.x,gm0.y,gm0.z,gm0.w, gm1.x,gm1.y,gm1.z,gm1.w};
    float bt[8] = {bt0.x,bt0.y,bt0.z,bt0.w, bt1.x,bt1.y,bt1.z,bt1.w};

#pragma unroll
    for (int r = 0; r < 8; ++r) {
        float v[8];
        float sm = 0.0f, sq = 0.0f;
#pragma unroll
        for (int q = 0; q < 8; ++q) {
            v[q] = acc[r][q] * rinv[r];
            sm += v[q]; sq += v[q] * v[q];
        }
#pragma unroll
        for (int off = 1; off < 8; off <<= 1) {
            sm += __shfl_xor(sm, off);
            sq += __shfl_xor(sq, off);
        }
        float mu  = sm * (1.0f / 64.0f);
        float var = sq * (1.0f / 64.0f) - mu * mu;
        float rs  = rsqrtf(var + 1e-5f);
        float o[8];
#pragma unroll
        for (int q = 0; q < 8; ++q) {
            float hn = (v[q] - mu) * rs * gm[q] + bt[q];
            o[q] = (hn > 0.0f) ? hn : (__expf(hn) - 1.0f);
        }
        float* gp = &gout[((size_t)m * NN + i0 + r) * 64 + tx * 8];
        *(float4*)gp       = make_float4(o[0], o[1], o[2], o[3]);
        *(float4*)(gp + 4) = make_float4(o[4], o[5], o[6], o[7]);
    }
}

// ---------------------------------------------------------------------------
// residual + gate*g, reshaped to sequence layout [B*N][T][H] (unchanged)
// ---------------------------------------------------------------------------
__global__ __launch_bounds__(256) void combine_kernel(
    const float* __restrict__ x,      // [B*S*N][32]
    const float* __restrict__ g1,     // [B*S*N][64]
    const float* __restrict__ res_W,  // [32][64]
    const float* __restrict__ res_b,  // [64]
    const float* __restrict__ alpha_p,
    float* __restrict__ seqout)       // [B*N][T][64]
{
    int row = blockIdx.x * 4 + (threadIdx.x >> 6);
    int h = threadIdx.x & 63;
    int mg = row >> 8, n = row & 255;
    int b = mg >> 6, s = mg & 63;
    const float* xr = x + (size_t)row * 32;
    float acc = res_b[h];
#pragma unroll
    for (int f4 = 0; f4 < 8; ++f4) {
        float4 xv = *(const float4*)&xr[f4 * 4];
        acc += xv.x * res_W[(f4*4    ) * 64 + h] + xv.y * res_W[(f4*4 + 1) * 64 + h]
             + xv.z * res_W[(f4*4 + 2) * 64 + h] + xv.w * res_W[(f4*4 + 3) * 64 + h];
    }
    float alpha = fminf(fmaxf(alpha_p[0], 0.0f), 1.0f);
    acc += alpha * g1[(size_t)row * 64 + h];
    seqout[(((size_t)(b * NN + n)) * TT + s) * 64 + h] = acc;
}

// ---------------------------------------------------------------------------
// W pre-convert: Wih[2][K][256] fp32 -> fragment-ordered bf16 hi/lo.
// idx = ((dir*NKC + kc)*16 + ng)*512 + g*128 + nl*8 + j
//   holds W[dir][kc*32 + 8*g + j][ng*16 + nl].
// ---------------------------------------------------------------------------
template<int K>
__global__ __launch_bounds__(256) void wcvt_kernel(
    const float* __restrict__ Wih, __bf16* __restrict__ Wh, __bf16* __restrict__ Wl)
{
    constexpr int NKC = K / 32;
    int idx = blockIdx.x * 256 + threadIdx.x;
    int j   = idx & 7;
    int nl  = (idx >> 3) & 15;
    int g   = (idx >> 7) & 3;
    int ng  = (idx >> 9) & 15;
    int rest = idx >> 13;                 // dir*NKC + kc
    int kc  = rest & (NKC - 1);
    int dir = rest / NKC;
    int k = kc * 32 + g * 8 + j;
    int n = ng * 16 + nl;
    float x = Wih[((size_t)dir * K + k) * 256 + n];
    __bf16 h = bfh(x);
    Wh[idx] = h;
    Wl[idx] = bfh(x - bf2f(h));
}

// ---------------------------------------------------------------------------
// Whh pre-convert (both layers, one launch): same frag layout as wcvt<64>.
// out: [layer][hi 32768 | lo 32768] bf16.
// ---------------------------------------------------------------------------
__global__ __launch_bounds__(256) void whhcvt_kernel(
    const float* __restrict__ W0, const float* __restrict__ W1,
    __bf16* __restrict__ outw)
{
    int idx = blockIdx.x * 256 + threadIdx.x;   // 0..65535
    int lay = idx >> 15;
    int r   = idx & 32767;
    int j   = r & 7;
    int nl  = (r >> 3) & 15;
    int g   = (r >> 7) & 3;
    int ng  = (r >> 9) & 15;
    int rest = r >> 13;                  // dir*2 + kc
    int kc  = rest & 1;
    int dir = rest >> 1;
    int k = kc * 32 + g * 8 + j;
    int n = ng * 16 + nl;
    const float* W = lay ? W1 : W0;
    float x = W[((size_t)dir * 64 + k) * 256 + n];
    __bf16 h = bfh(x);
    outw[lay * 65536 + r]         = h;
    outw[lay * 65536 + 32768 + r] = bfh(x - bf2f(h));
}

// ---------------------------------------------------------------------------
// xg GEMM via split-bf16 MFMA — GATE-GROUPED wave columns + coalesced float4
// epilogue into [k][gate] (colp) layout (unchanged from r10).
// ---------------------------------------------------------------------------
template<int K>
__global__ __launch_bounds__(256, 2) void xg_mfma_kernel(
    const float* __restrict__ A,       // [MROWS][K]
    const __bf16* __restrict__ Wh,     // frag-ordered
    const __bf16* __restrict__ Wl,
    const float* __restrict__ bih,     // [2][256]
    const float* __restrict__ bhh,     // [2][256]
    float* __restrict__ xg)            // [2][MROWS][64k][4g]
{
    constexpr int NKC = K / 32;
    __shared__ __bf16 a_h[2][128 * 32];
    __shared__ __bf16 a_l[2][128 * 32];

    const int tid  = threadIdx.x;
    const int lane = tid & 63;
    const int w    = tid >> 6;
    const int wr   = w >> 1, wc = w & 1;

    int bid = blockIdx.x;
    int wg  = (bid >> 3) | ((bid & 7) << 8);
    int cd  = wg & 3;
    int m0  = (wg >> 2) * 128;
    int dir = cd >> 1;
    const int kq = (cd & 1) * 2 + wc;    // wave's 16-k group (0..3)

    f32x4 acc[4][4];
#pragma unroll
    for (int mi = 0; mi < 4; ++mi)
#pragma unroll
        for (int ni = 0; ni < 4; ++ni)
            acc[mi][ni] = (f32x4){0.0f, 0.0f, 0.0f, 0.0f};

    const int srow = tid >> 1;
    const int g0   = (tid & 1) * 2;
    const float* abase = A + (size_t)(m0 + srow) * K + (tid & 1) * 16;
    const int soff0 = srow * 32 + (( g0      ^ (srow & 3)) * 8);
    const int soff1 = srow * 32 + (((g0 + 1) ^ (srow & 3)) * 8);

    int aoff[4];
#pragma unroll
    for (int mi = 0; mi < 4; ++mi)
        aoff[mi] = (wr * 64 + mi * 16 + (lane & 15)) * 32
                 + (((lane >> 4) ^ (lane & 3)) * 8);

    auto cvtstore = [&](const float* f, int buf) {
        bf16x8 h0, h1, l0, l1;
#pragma unroll
        for (int i = 0; i < 8; ++i) {
            __bf16 ha = bfh(f[i]);
            __bf16 hb = bfh(f[8 + i]);
            h0[i] = ha; l0[i] = bfh(f[i]     - bf2f(ha));
            h1[i] = hb; l1[i] = bfh(f[8 + i] - bf2f(hb));
        }
        *(bf16x8*)&a_h[buf][soff0] = h0;
        *(bf16x8*)&a_h[buf][soff1] = h1;
        *(bf16x8*)&a_l[buf][soff0] = l0;
        *(bf16x8*)&a_l[buf][soff1] = l1;
    };

    {
        float f[16];
#pragma unroll
        for (int i = 0; i < 4; ++i) {
            float4 v = *(const float4*)(abase + i * 4);
            f[i*4+0] = v.x; f[i*4+1] = v.y; f[i*4+2] = v.z; f[i*4+3] = v.w;
        }
        cvtstore(f, 0);
    }
    __syncthreads();

    int buf = 0;
    for (int kc = 0; kc < NKC; ++kc) {
        float f[16];
        if (kc + 1 < NKC) {
#pragma unroll
            for (int i = 0; i < 4; ++i) {
                float4 v = *(const float4*)(abase + (kc + 1) * 32 + i * 4);
                f[i*4+0] = v.x; f[i*4+1] = v.y; f[i*4+2] = v.z; f[i*4+3] = v.w;
            }
        }
        bf16x8 bh[4], bl[4];
#pragma unroll
        for (int ni = 0; ni < 4; ++ni) {   // ni = gate
            size_t fb = ((size_t)((dir * NKC + kc) * 16 + ni * 4 + kq)) * 512 + lane * 8;
            bh[ni] = *(const bf16x8*)(Wh + fb);
            bl[ni] = *(const bf16x8*)(Wl + fb);
        }
        bf16x8 ah[4], al[4];
#pragma unroll
        for (int mi = 0; mi < 4; ++mi) {
            ah[mi] = *(const bf16x8*)&a_h[buf][aoff[mi]];
            al[mi] = *(const bf16x8*)&a_l[buf][aoff[mi]];
        }
#pragma unroll
        for (int mi = 0; mi < 4; ++mi)
#pragma unroll
            for (int ni = 0; ni < 4; ++ni)
                acc[mi][ni] = __builtin_amdgcn_mfma_f32_16x16x32_bf16(
                    ah[mi], bh[ni], acc[mi][ni], 0, 0, 0);
#pragma unroll
        for (int mi = 0; mi < 4; ++mi)
#pragma unroll
            for (int ni = 0; ni < 4; ++ni)
                acc[mi][ni] = __builtin_amdgcn_mfma_f32_16x16x32_bf16(
                    al[mi], bh[ni], acc[mi][ni], 0, 0, 0);
#pragma unroll
        for (int mi = 0; mi < 4; ++mi)
#pragma unroll
            for (int ni = 0; ni < 4; ++ni)
                acc[mi][ni] = __builtin_amdgcn_mfma_f32_16x16x32_bf16(
                    ah[mi], bl[ni], acc[mi][ni], 0, 0, 0);

        if (kc + 1 < NKC) cvtstore(f, buf ^ 1);
        __syncthreads();
        buf ^= 1;
    }

    // epilogue: assemble i,f,g,o per (row,k) into one coalesced float4
    const int kcol = kq * 16 + (lane & 15);
    float bias4[4];
#pragma unroll
    for (int g = 0; g < 4; ++g)
        bias4[g] = bih[dir * 256 + g * 64 + kcol] + bhh[dir * 256 + g * 64 + kcol];
#pragma unroll
    for (int mi = 0; mi < 4; ++mi) {
        int mrow = m0 + wr * 64 + mi * 16 + ((lane >> 4) << 2);
#pragma unroll
        for (int r = 0; r < 4; ++r) {
            float4 v = make_float4(acc[mi][0][r] + bias4[0], acc[mi][1][r] + bias4[1],
                                   acc[mi][2][r] + bias4[2], acc[mi][3][r] + bias4[3]);
            *(float4*)&xg[((size_t)dir * MROWS + mrow + r) * 256 + kcol * 4] = v;
        }
    }
}

// ---------------------------------------------------------------------------
// LSTM recurrence v10 = v9 + PING-PONG prefetch registers (2x unrolled steps).
// The v9 end-of-step `xc = xn` register copy forced a vmcnt(0) wait in the
// SAME step the loads were issued — exposing L3/HBM latency every step.
// Ping-pong (even: consume xa / prefetch xb; odd: reverse) moves the wait
// to the use point one FULL step later (~1000+ cy slack).
// ---------------------------------------------------------------------------
__global__ __launch_bounds__(256, 2) void lstm_rec_kernel(
    const float* __restrict__ xg,     // [2][NSEQ][T][64k][4g]
    const __bf16* __restrict__ whhf,  // [hi 32768 | lo 32768] frag-ordered
    float* __restrict__ out,
    int write_all)
{
    const int tid  = threadIdx.x;
    const int wv   = tid >> 6;        // wave 0..3 = k-slice
    const int lane = tid & 63;
    const int nl   = lane & 15;
    const int lq   = lane >> 4;

    const int bid  = blockIdx.x;      // grid 512
    const int dir  = bid & 1;
    const int seq0 = (bid >> 1) * 4;  // 4 seqs per block

    // B fragments: Whh' hi/lo, held in VGPRs for the whole kernel
    const __bf16* wh = whhf;
    const __bf16* wl = whhf + 32768;
    bf16x8 bh[2][4], bl[2][4];
#pragma unroll
    for (int kc = 0; kc < 2; ++kc)
#pragma unroll
        for (int g = 0; g < 4; ++g) {
            size_t fb = ((size_t)((dir * 2 + kc) * 16 + g * 4 + wv)) * 512 + lane * 8;
            bh[kc][g] = *(const bf16x8*)(wh + fb);
            bl[kc][g] = *(const bf16x8*)(wl + fb);
        }

    // h broadcast buffers: [parity][s(16)][k(64)] bf16, XOR-swizzled on k>>3
    __shared__ __align__(16) __bf16 h_hi[2048];
    __shared__ __align__(16) __bf16 h_lo[2048];
    {
        uint4 z = {0, 0, 0, 0};
        *(uint4*)&h_hi[tid * 8] = z;
        *(uint4*)&h_lo[tid * 8] = z;
    }

    const int k   = wv * 16 + nl;     // this lane's hidden index (cell phase)
    const int g8k = k >> 3;

    float c[4] = {0.0f, 0.0f, 0.0f, 0.0f};
    float4 xa[4] = {}, xb[4] = {};

    // stepping pointers
    const float* pxg = xg + (((size_t)dir * NSEQ + seq0) * TT
                             + (dir ? (TT - 1) : 0)) * 256 + k * 4;
    const int dstep = dir ? -256 : 256;
    float* pout = out + ((size_t)seq0 * TT + (dir ? (TT - 1) : 0)) * 128
                + dir * 64 + k;
    const int ostep = dir ? -128 : 128;

    auto load_xg = [&](float4 (&d)[4]) {
        if (lane < 16) {
#pragma unroll
            for (int r = 0; r < 4; ++r)
                d[r] = *(const float4*)(pxg + (size_t)r * TT * 256);
        }
        pxg += dstep;
    };

    int buf = 0;
    auto step_body = [&](int step, float4 (&xcur)[4], float4 (&xnext)[4], bool pre) {
        // A fragments: h(step) from LDS buf
        const int aof0 = buf * 1024 + nl * 64 + (((0 + lq) ^ (nl & 7)) * 8);
        const int aof1 = buf * 1024 + nl * 64 + (((4 + lq) ^ (nl & 7)) * 8);
        bf16x8 ah0 = *(const bf16x8*)&h_hi[aof0];
        bf16x8 ah1 = *(const bf16x8*)&h_hi[aof1];
        bf16x8 al0 = *(const bf16x8*)&h_lo[aof0];
        bf16x8 al1 = *(const bf16x8*)&h_lo[aof1];

        if (pre) load_xg(xnext);          // stays in flight a FULL step

        f32x4 acc[4];
#pragma unroll
        for (int g = 0; g < 4; ++g) acc[g] = (f32x4){0.0f, 0.0f, 0.0f, 0.0f};
#pragma unroll
        for (int g = 0; g < 4; ++g)
            acc[g] = __builtin_amdgcn_mfma_f32_16x16x32_bf16(ah0, bh[0][g], acc[g], 0, 0, 0);
#pragma unroll
        for (int g = 0; g < 4; ++g)
            acc[g] = __builtin_amdgcn_mfma_f32_16x16x32_bf16(ah1, bh[1][g], acc[g], 0, 0, 0);
#pragma unroll
        for (int g = 0; g < 4; ++g)
            acc[g] = __builtin_amdgcn_mfma_f32_16x16x32_bf16(al0, bh[0][g], acc[g], 0, 0, 0);
#pragma unroll
        for (int g = 0; g < 4; ++g)
            acc[g] = __builtin_amdgcn_mfma_f32_16x16x32_bf16(al1, bh[1][g], acc[g], 0, 0, 0);
#pragma unroll
        for (int g = 0; g < 4; ++g)
            acc[g] = __builtin_amdgcn_mfma_f32_16x16x32_bf16(ah0, bl[0][g], acc[g], 0, 0, 0);
#pragma unroll
        for (int g = 0; g < 4; ++g)
            acc[g] = __builtin_amdgcn_mfma_f32_16x16x32_bf16(ah1, bl[1][g], acc[g], 0, 0, 0);

        if (lane < 16) {
            // seqs 0..3 in acc rows 0..3 (lq==0 lanes)
#pragma unroll
            for (int r = 0; r < 4; ++r) {
                float iv = sigmoid_f(acc[0][r] + xcur[r].x);
                float fv = sigmoid_f(acc[1][r] + xcur[r].y);
                float gv = tanh_f  (acc[2][r] + xcur[r].z);
                float ov = sigmoid_f(acc[3][r] + xcur[r].w);
                c[r] = fv * c[r] + iv * gv;
                float h = ov * tanh_f(c[r]);
                int off = (buf ^ 1) * 1024 + r * 64 + ((g8k ^ r) * 8) + (k & 7);
                __bf16 hh = bfh(h);
                h_hi[off] = hh;
                h_lo[off] = bfh(h - bf2f(hh));
                if (write_all)
                    pout[(size_t)r * TT * 128] = h;
                else if (step == TT - 1)
                    out[(size_t)(seq0 + r) * 128 + dir * 64 + k] = h;
            }
        }
        pout += ostep;
        lds_barrier();
        buf ^= 1;
    };

    load_xg(xa);                           // t=0
    lds_barrier();

    for (int step = 0; step < TT; step += 2) {
        step_body(step,     xa, xb, true);             // consume xa, fetch t+1
        step_body(step + 1, xb, xa, step + 2 < TT);    // consume xb, fetch t+2
    }
}

// ---------------------------------------------------------------------------
__global__ __launch_bounds__(256) void fc_kernel(
    const float* __restrict__ fin,   // [NSEQ][128]
    const float* __restrict__ fc_W,  // [128]
    const float* __restrict__ fc_b,  // [1]
    float* __restrict__ outp)        // [NSEQ]
{
    int s = blockIdx.x * 256 + threadIdx.x;
    const float* fr = fin + (size_t)s * 128;
    float acc = fc_b[0];
#pragma unroll
    for (int k4 = 0; k4 < 32; ++k4) {
        float4 fv = *(const float4*)&fr[k4 * 4];
        float4 wv2 = *(const float4*)&fc_W[k4 * 4];
        acc += fv.x * wv2.x + fv.y * wv2.y + fv.z * wv2.z + fv.w * wv2.w;
    }
    outp[s] = acc;
}

// ---------------------------------------------------------------------------
extern "C" void kernel_launch(void* const* d_in, const int* in_sizes, int n_in,
                              void* d_out, int out_size, void* d_ws, size_t ws_size,
                              hipStream_t stream) {
    const float* x       = (const float*)d_in[0];
    const float* adj     = (const float*)d_in[1];
    const float* gat0_W  = (const float*)d_in[2];
    const float* gat0_a  = (const float*)d_in[3];
    const float* gat0_g  = (const float*)d_in[4];
    const float* gat0_b  = (const float*)d_in[5];
    const float* gat1_W  = (const float*)d_in[6];
    const float* gat1_a  = (const float*)d_in[7];
    const float* gat1_g  = (const float*)d_in[8];
    const float* gat1_b  = (const float*)d_in[9];
    const float* res_W   = (const float*)d_in[10];
    const float* res_b   = (const float*)d_in[11];
    const float* alpha_g = (const float*)d_in[12];
    const float* l0_Wih  = (const float*)d_in[13];
    const float* l0_Whh  = (const float*)d_in[14];
    const float* l0_bih  = (const float*)d_in[15];
    const float* l0_bhh  = (const float*)d_in[16];
    const float* l1_Wih  = (const float*)d_in[17];
    const float* l1_Whh  = (const float*)d_in[18];
    const float* l1_bih  = (const float*)d_in[19];
    const float* l1_bhh  = (const float*)d_in[20];
    const float* fc_W    = (const float*)d_in[21];
    const float* fc_b    = (const float*)d_in[22];

    float* ws = (float*)d_ws;
    float* g0    = ws;                    // [M][N][64]
    float* g1    = ws + 4194304;          // [M][N][64]
    float* seq   = ws + 8388608;          // [B*N][T][64]
    float* xg    = ws + 12582912;         // [2][65536][256]
    float* fin   = ws + 46137344;         // [NSEQ][128]
    float* o1    = ws;                    // reuse g0+g1 [NSEQ][T][128]

    // Wih' (bf16 hi/lo, frag-ordered) OVERLAPS fin: lifetimes disjoint
    __bf16* w0h = (__bf16*)(ws + 46137344);
    __bf16* w0l = w0h + 2 * 64 * 256;
    __bf16* w1h = w0l + 2 * 64 * 256;
    __bf16* w1l = w1h + 2 * 128 * 256;

    // Whh' frags live in the seq region (dead after xg_mfma<64>)
    __bf16* whhf = (__bf16*)seq;          // [2 layers][hi 32768 | lo 32768]

    wcvt_kernel<64><<<128, 256, 0, stream>>>(l0_Wih, w0h, w0l);
    wcvt_kernel<128><<<256, 256, 0, stream>>>(l1_Wih, w1h, w1l);
    gat_kernel<32><<<MM, 256, 0, stream>>>(x, adj, gat0_W, gat0_a, gat0_g, gat0_b, g0);
    gat_kernel<64><<<MM, 256, 0, stream>>>(g0, adj, gat1_W, gat1_a, gat1_g, gat1_b, g1);
    combine_kernel<<<(BB*SS*NN)/4, 256, 0, stream>>>(x, g1, res_W, res_b, alpha_g, seq);
    xg_mfma_kernel<64><<<2048, 256, 0, stream>>>(seq, w0h, w0l, l0_bih, l0_bhh, xg);
    whhcvt_kernel<<<256, 256, 0, stream>>>(l0_Whh, l1_Whh, whhf);
    lstm_rec_kernel<<<512, 256, 0, stream>>>(xg, whhf, o1, 1);
    xg_mfma_kernel<128><<<2048, 256, 0, stream>>>(o1, w1h, w1l, l1_bih, l1_bhh, xg);
    lstm_rec_kernel<<<512, 256, 0, stream>>>(xg, whhf + 65536, fin, 0);
    fc_kernel<<<NSEQ/256, 256, 0, stream>>>(fin, fc_W, fc_b, (float*)d_out);
}

// Round 13
// 531.852 us; speedup vs baseline: 1.0923x; 1.0568x over previous
//
#include <hip/hip_runtime.h>
#include <math.h>

// Problem constants
#define BB 4
#define SS 64
#define NN 256
#define FF 32
#define HH 64
#define MM (BB*SS)      // 256 graphs
#define NSEQ (BB*NN)    // 1024 sequences
#define TT SS           // 64 timesteps
#define MROWS (NSEQ*TT) // 65536 GEMM rows

// fast activations: v_rcp_f32 (~1ulp) instead of IEEE divide
__device__ __forceinline__ float fast_rcp(float x) { return __builtin_amdgcn_rcpf(x); }
__device__ __forceinline__ float sigmoid_f(float x) { return fast_rcp(1.0f + __expf(-x)); }
__device__ __forceinline__ float tanh_f(float x) {
    float t = __expf(-2.0f * fabsf(x));
    float r = (1.0f - t) * fast_rcp(1.0f + t);
    return copysignf(r, x);
}

// LDS-only barrier: waits ONLY lgkmcnt (LDS) before s_barrier, leaving global
// prefetch loads / stores IN FLIGHT across the barrier.
// sched_barrier(0) pins post-barrier ds_reads (guide rule #18).
__device__ __forceinline__ void lds_barrier() {
    asm volatile("s_waitcnt lgkmcnt(0)" ::: "memory");
    __builtin_amdgcn_s_barrier();
    __builtin_amdgcn_sched_barrier(0);
}

// ---- bf16 split helpers (RTNE hi, hi+lo captures ~17 mantissa bits) ----
typedef __bf16 bf16x8 __attribute__((ext_vector_type(8)));
typedef float  f32x4  __attribute__((ext_vector_type(4)));

__device__ __forceinline__ __bf16 bfh(float x) {
    unsigned u = __float_as_uint(x);
    unsigned r = (u + 0x7FFFu + ((u >> 16) & 1u)) >> 16;
    return __builtin_bit_cast(__bf16, (unsigned short)r);
}
__device__ __forceinline__ float bf2f(__bf16 b) {
    unsigned u = ((unsigned)__builtin_bit_cast(unsigned short, b)) << 16;
    return __uint_as_float(u);
}

// ---------------------------------------------------------------------------
// GAT layer v3: MFMA aggregation.
// Per block = 1 graph, 256 threads (4 waves).
// Phase A: h = x@W (fp32, VALU) into U region [256][68].
// Conversion: thread tid pulls row tid to regs, computes s1/s2, then U is
//   REUSED as transposed bf16 frags F[64 c][264 pad] (hi|lo).
// Chunk loop (8 x k=32): thread tid computes p[tid][kk] (exp, unnormalized),
//   converts to bf16 hi/lo into p_hi/p_lo[256][40 pad]; each wave then does
//   48 MFMAs (3-term split) for its 64-row output slab. adj prefetched one
//   chunk ahead; lds_barrier keeps the prefetch in flight.
// Epilogue: normalize by srow, LN via shfl over 16-lane col-groups, ELU.
// C/D layout (verified): col=lane&15, row=(lane>>4)*4+r. A/B share the
// k-bijection k = lq*8+j (cancels any HW permutation — same as xg_mfma).
// LDS: 68K (U/F union) + 40K (p) + 3K = 113.7 KB -> 1 block/CU.
// ---------------------------------------------------------------------------
template<int FIN>
__global__ __launch_bounds__(256) void gat_kernel(
    const float* __restrict__ xin,   // [M][N][FIN]
    const float* __restrict__ adj,   // [M][N][N]
    const float* __restrict__ W,     // [FIN][64]
    const float* __restrict__ a,     // [128]
    const float* __restrict__ gamma_, const float* __restrict__ beta_,
    float* __restrict__ gout)        // [M][N][64]
{
    __shared__ __align__(16) float u_f32[256 * 68];     // 69632 B, reused as F
    __shared__ __align__(16) __bf16 p_hi[256 * 40];     // 20480 B
    __shared__ __align__(16) __bf16 p_lo[256 * 40];
    __shared__ float s1s[256], s2s[256], srow[256];

    __bf16* F_hi = (__bf16*)u_f32;          // [64][264] bf16 (33792 B)
    __bf16* F_lo = F_hi + 64 * 264;         // (+33792 B <= 69632) OK

    const int m    = blockIdx.x;
    const int tid  = threadIdx.x;
    const int lane = tid & 63;
    const int wv   = tid >> 6;
    const int nl   = lane & 15;
    const int lq   = lane >> 4;

    // ---- Phase A: h = x @ W -> U (fp32, stride 68) ----
    {
        const int c = tid & 63;
        const int w = tid >> 6;
        float wreg[FIN];
#pragma unroll
        for (int f = 0; f < FIN; ++f) wreg[f] = W[f * 64 + c];
        const float* xm = xin + (size_t)m * NN * FIN;
        for (int i0 = 0; i0 < 64; ++i0) {
            int i = (i0 << 2) | w;
            float acc = 0.0f;
#pragma unroll
            for (int f4 = 0; f4 < FIN / 4; ++f4) {
                float4 xv = *(const float4*)&xm[i * FIN + f4 * 4];
                acc += xv.x * wreg[f4*4] + xv.y * wreg[f4*4+1]
                     + xv.z * wreg[f4*4+2] + xv.w * wreg[f4*4+3];
            }
            u_f32[i * 68 + c] = acc;
        }
    }
    __syncthreads();

    // ---- Conversion: row tid -> regs; s1/s2; then U reused as F (bf16) ----
    float hr[64];
    {
        const float* hp = &u_f32[tid * 68];
        float acc1 = 0.0f, acc2 = 0.0f;
#pragma unroll
        for (int c4 = 0; c4 < 16; ++c4) {
            float4 hv = *(const float4*)&hp[c4 * 4];
            hr[c4*4+0] = hv.x; hr[c4*4+1] = hv.y; hr[c4*4+2] = hv.z; hr[c4*4+3] = hv.w;
            float4 av1 = *(const float4*)&a[c4 * 4];
            float4 av2 = *(const float4*)&a[64 + c4 * 4];
            acc1 += hv.x * av1.x + hv.y * av1.y + hv.z * av1.z + hv.w * av1.w;
            acc2 += hv.x * av2.x + hv.y * av2.y + hv.z * av2.z + hv.w * av2.w;
        }
        s1s[tid] = acc1; s2s[tid] = acc2;
    }
    __syncthreads();                       // ALL U reads done before overwrite
    {
#pragma unroll
        for (int c = 0; c < 64; ++c) {
            __bf16 hh = bfh(hr[c]);
            F_hi[c * 264 + tid] = hh;
            F_lo[c * 264 + tid] = bfh(hr[c] - bf2f(hh));
        }
    }

    // ---- chunk loop: p staging + MFMA ----
    const float* adjr = adj + ((size_t)m * NN + tid) * NN;
    const float s1v = s1s[tid];
    float srow_acc = 0.0f;

    f32x4 acc[4][4];
#pragma unroll
    for (int mt = 0; mt < 4; ++mt)
#pragma unroll
        for (int nt = 0; nt < 4; ++nt)
            acc[mt][nt] = (f32x4){0.0f, 0.0f, 0.0f, 0.0f};

    float4 adjreg[8];
#pragma unroll
    for (int q = 0; q < 8; ++q) adjreg[q] = *(const float4*)&adjr[q * 4];

    for (int ch = 0; ch < 8; ++ch) {
        // make_p: 32 unnormalized attention weights for row tid
        {
            float pv[32];
#pragma unroll
            for (int q = 0; q < 8; ++q) {
                float4 av = adjreg[q];
                float4 sv = *(const float4*)&s2s[ch * 32 + q * 4];
                float e0 = s1v + sv.x, e1 = s1v + sv.y, e2 = s1v + sv.z, e3 = s1v + sv.w;
                e0 = (e0 > 0.0f) ? e0 : 0.2f * e0;
                e1 = (e1 > 0.0f) ? e1 : 0.2f * e1;
                e2 = (e2 > 0.0f) ? e2 : 0.2f * e2;
                e3 = (e3 > 0.0f) ? e3 : 0.2f * e3;
                float p0 = (av.x > 0.0f) ? __expf(e0) : 0.0f;
                float p1 = (av.y > 0.0f) ? __expf(e1) : 0.0f;
                float p2 = (av.z > 0.0f) ? __expf(e2) : 0.0f;
                float p3 = (av.w > 0.0f) ? __expf(e3) : 0.0f;
                srow_acc += (p0 + p1) + (p2 + p3);
                pv[q*4+0] = p0; pv[q*4+1] = p1; pv[q*4+2] = p2; pv[q*4+3] = p3;
            }
#pragma unroll
            for (int b = 0; b < 4; ++b) {
                bf16x8 h8, l8;
#pragma unroll
                for (int j = 0; j < 8; ++j) {
                    __bf16 hh = bfh(pv[b*8+j]);
                    h8[j] = hh;
                    l8[j] = bfh(pv[b*8+j] - bf2f(hh));
                }
                *(bf16x8*)&p_hi[tid * 40 + b * 8] = h8;
                *(bf16x8*)&p_lo[tid * 40 + b * 8] = l8;
            }
        }
        if (ch < 7) {                     // prefetch next adj chunk (in flight)
#pragma unroll
            for (int q = 0; q < 8; ++q)
                adjreg[q] = *(const float4*)&adjr[(ch + 1) * 32 + q * 4];
        }
        lds_barrier();                    // p (and F, first iter) visible

        // MFMA: wave wv owns rows [wv*64, wv*64+64)
        bf16x8 pah[4], pal[4], fbh[4], fbl[4];
#pragma unroll
        for (int mt = 0; mt < 4; ++mt) {
            int row = wv * 64 + mt * 16 + nl;
            pah[mt] = *(const bf16x8*)&p_hi[row * 40 + lq * 8];
            pal[mt] = *(const bf16x8*)&p_lo[row * 40 + lq * 8];
        }
#pragma unroll
        for (int nt = 0; nt < 4; ++nt) {
            int fo = (nt * 16 + nl) * 264 + ch * 32 + lq * 8;
            fbh[nt] = *(const bf16x8*)&F_hi[fo];
            fbl[nt] = *(const bf16x8*)&F_lo[fo];
        }
#pragma unroll
        for (int mt = 0; mt < 4; ++mt)
#pragma unroll
            for (int nt = 0; nt < 4; ++nt)
                acc[mt][nt] = __builtin_amdgcn_mfma_f32_16x16x32_bf16(
                    pah[mt], fbh[nt], acc[mt][nt], 0, 0, 0);
#pragma unroll
        for (int mt = 0; mt < 4; ++mt)
#pragma unroll
            for (int nt = 0; nt < 4; ++nt)
                acc[mt][nt] = __builtin_amdgcn_mfma_f32_16x16x32_bf16(
                    pal[mt], fbh[nt], acc[mt][nt], 0, 0, 0);
#pragma unroll
        for (int mt = 0; mt < 4; ++mt)
#pragma unroll
            for (int nt = 0; nt < 4; ++nt)
                acc[mt][nt] = __builtin_amdgcn_mfma_f32_16x16x32_bf16(
                    pah[mt], fbl[nt], acc[mt][nt], 0, 0, 0);

        lds_barrier();                    // MFMA reads done before p overwrite
    }

    srow[tid] = srow_acc;
    __syncthreads();

    // ---- epilogue: normalize, LN over 64 cols (shfl over nl bits), ELU ----
    float gm[4], bt[4];
#pragma unroll
    for (int nt = 0; nt < 4; ++nt) {
        gm[nt] = gamma_[nt * 16 + nl];
        bt[nt] = beta_[nt * 16 + nl];
    }
#pragma unroll
    for (int mt = 0; mt < 4; ++mt) {
#pragma unroll
        for (int r = 0; r < 4; ++r) {
            int row = wv * 64 + mt * 16 + lq * 4 + r;
            float rinv = fast_rcp(srow[row]);
            float v[4];
            float sm = 0.0f, sq = 0.0f;
#pragma unroll
            for (int nt = 0; nt < 4; ++nt) {
                v[nt] = acc[mt][nt][r] * rinv;
                sm += v[nt]; sq += v[nt] * v[nt];
            }
#pragma unroll
            for (int off = 1; off < 16; off <<= 1) {
                sm += __shfl_xor(sm, off);
                sq += __shfl_xor(sq, off);
            }
            float mu  = sm * (1.0f / 64.0f);
            float var = sq * (1.0f / 64.0f) - mu * mu;
            float rs  = rsqrtf(var + 1e-5f);
            float* gp = &gout[((size_t)m * NN + row) * 64];
#pragma unroll
            for (int nt = 0; nt < 4; ++nt) {
                float hn = (v[nt] - mu) * rs * gm[nt] + bt[nt];
                gp[nt * 16 + nl] = (hn > 0.0f) ? hn : (__expf(hn) - 1.0f);
            }
        }
    }
}

// ---------------------------------------------------------------------------
// residual + gate*g, reshaped to sequence layout [B*N][T][H] (unchanged)
// ---------------------------------------------------------------------------
__global__ __launch_bounds__(256) void combine_kernel(
    const float* __restrict__ x,      // [B*S*N][32]
    const float* __restrict__ g1,     // [B*S*N][64]
    const float* __restrict__ res_W,  // [32][64]
    const float* __restrict__ res_b,  // [64]
    const float* __restrict__ alpha_p,
    float* __restrict__ seqout)       // [B*N][T][64]
{
    int row = blockIdx.x * 4 + (threadIdx.x >> 6);
    int h = threadIdx.x & 63;
    int mg = row >> 8, n = row & 255;
    int b = mg >> 6, s = mg & 63;
    const float* xr = x + (size_t)row * 32;
    float acc = res_b[h];
#pragma unroll
    for (int f4 = 0; f4 < 8; ++f4) {
        float4 xv = *(const float4*)&xr[f4 * 4];
        acc += xv.x * res_W[(f4*4    ) * 64 + h] + xv.y * res_W[(f4*4 + 1) * 64 + h]
             + xv.z * res_W[(f4*4 + 2) * 64 + h] + xv.w * res_W[(f4*4 + 3) * 64 + h];
    }
    float alpha = fminf(fmaxf(alpha_p[0], 0.0f), 1.0f);
    acc += alpha * g1[(size_t)row * 64 + h];
    seqout[(((size_t)(b * NN + n)) * TT + s) * 64 + h] = acc;
}

// ---------------------------------------------------------------------------
// W pre-convert: Wih[2][K][256] fp32 -> fragment-ordered bf16 hi/lo.
// idx = ((dir*NKC + kc)*16 + ng)*512 + g*128 + nl*8 + j
//   holds W[dir][kc*32 + 8*g + j][ng*16 + nl].
// ---------------------------------------------------------------------------
template<int K>
__global__ __launch_bounds__(256) void wcvt_kernel(
    const float* __restrict__ Wih, __bf16* __restrict__ Wh, __bf16* __restrict__ Wl)
{
    constexpr int NKC = K / 32;
    int idx = blockIdx.x * 256 + threadIdx.x;
    int j   = idx & 7;
    int nl  = (idx >> 3) & 15;
    int g   = (idx >> 7) & 3;
    int ng  = (idx >> 9) & 15;
    int rest = idx >> 13;                 // dir*NKC + kc
    int kc  = rest & (NKC - 1);
    int dir = rest / NKC;
    int k = kc * 32 + g * 8 + j;
    int n = ng * 16 + nl;
    float x = Wih[((size_t)dir * K + k) * 256 + n];
    __bf16 h = bfh(x);
    Wh[idx] = h;
    Wl[idx] = bfh(x - bf2f(h));
}

// ---------------------------------------------------------------------------
// Whh pre-convert (both layers, one launch): same frag layout as wcvt<64>.
// out: [layer][hi 32768 | lo 32768] bf16.
// ---------------------------------------------------------------------------
__global__ __launch_bounds__(256) void whhcvt_kernel(
    const float* __restrict__ W0, const float* __restrict__ W1,
    __bf16* __restrict__ outw)
{
    int idx = blockIdx.x * 256 + threadIdx.x;   // 0..65535
    int lay = idx >> 15;
    int r   = idx & 32767;
    int j   = r & 7;
    int nl  = (r >> 3) & 15;
    int g   = (r >> 7) & 3;
    int ng  = (r >> 9) & 15;
    int rest = r >> 13;                  // dir*2 + kc
    int kc  = rest & 1;
    int dir = rest >> 1;
    int k = kc * 32 + g * 8 + j;
    int n = ng * 16 + nl;
    const float* W = lay ? W1 : W0;
    float x = W[((size_t)dir * 64 + k) * 256 + n];
    __bf16 h = bfh(x);
    outw[lay * 65536 + r]         = h;
    outw[lay * 65536 + 32768 + r] = bfh(x - bf2f(h));
}

// ---------------------------------------------------------------------------
// xg GEMM via split-bf16 MFMA — GATE-GROUPED wave columns + coalesced float4
// epilogue into [k][gate] (colp) layout (unchanged).
// ---------------------------------------------------------------------------
template<int K>
__global__ __launch_bounds__(256, 2) void xg_mfma_kernel(
    const float* __restrict__ A,       // [MROWS][K]
    const __bf16* __restrict__ Wh,     // frag-ordered
    const __bf16* __restrict__ Wl,
    const float* __restrict__ bih,     // [2][256]
    const float* __restrict__ bhh,     // [2][256]
    float* __restrict__ xg)            // [2][MROWS][64k][4g]
{
    constexpr int NKC = K / 32;
    __shared__ __bf16 a_h[2][128 * 32];
    __shared__ __bf16 a_l[2][128 * 32];

    const int tid  = threadIdx.x;
    const int lane = tid & 63;
    const int w    = tid >> 6;
    const int wr   = w >> 1, wc = w & 1;

    int bid = blockIdx.x;
    int wg  = (bid >> 3) | ((bid & 7) << 8);
    int cd  = wg & 3;
    int m0  = (wg >> 2) * 128;
    int dir = cd >> 1;
    const int kq = (cd & 1) * 2 + wc;    // wave's 16-k group (0..3)

    f32x4 acc[4][4];
#pragma unroll
    for (int mi = 0; mi < 4; ++mi)
#pragma unroll
        for (int ni = 0; ni < 4; ++ni)
            acc[mi][ni] = (f32x4){0.0f, 0.0f, 0.0f, 0.0f};

    const int srow = tid >> 1;
    const int g0   = (tid & 1) * 2;
    const float* abase = A + (size_t)(m0 + srow) * K + (tid & 1) * 16;
    const int soff0 = srow * 32 + (( g0      ^ (srow & 3)) * 8);
    const int soff1 = srow * 32 + (((g0 + 1) ^ (srow & 3)) * 8);

    int aoff[4];
#pragma unroll
    for (int mi = 0; mi < 4; ++mi)
        aoff[mi] = (wr * 64 + mi * 16 + (lane & 15)) * 32
                 + (((lane >> 4) ^ (lane & 3)) * 8);

    auto cvtstore = [&](const float* f, int buf) {
        bf16x8 h0, h1, l0, l1;
#pragma unroll
        for (int i = 0; i < 8; ++i) {
            __bf16 ha = bfh(f[i]);
            __bf16 hb = bfh(f[8 + i]);
            h0[i] = ha; l0[i] = bfh(f[i]     - bf2f(ha));
            h1[i] = hb; l1[i] = bfh(f[8 + i] - bf2f(hb));
        }
        *(bf16x8*)&a_h[buf][soff0] = h0;
        *(bf16x8*)&a_h[buf][soff1] = h1;
        *(bf16x8*)&a_l[buf][soff0] = l0;
        *(bf16x8*)&a_l[buf][soff1] = l1;
    };

    {
        float f[16];
#pragma unroll
        for (int i = 0; i < 4; ++i) {
            float4 v = *(const float4*)(abase + i * 4);
            f[i*4+0] = v.x; f[i*4+1] = v.y; f[i*4+2] = v.z; f[i*4+3] = v.w;
        }
        cvtstore(f, 0);
    }
    __syncthreads();

    int buf = 0;
    for (int kc = 0; kc < NKC; ++kc) {
        float f[16];
        if (kc + 1 < NKC) {
#pragma unroll
            for (int i = 0; i < 4; ++i) {
                float4 v = *(const float4*)(abase + (kc + 1) * 32 + i * 4);
                f[i*4+0] = v.x; f[i*4+1] = v.y; f[i*4+2] = v.z; f[i*4+3] = v.w;
            }
        }
        bf16x8 bh[4], bl[4];
#pragma unroll
        for (int ni = 0; ni < 4; ++ni) {   // ni = gate
            size_t fb = ((size_t)((dir * NKC + kc) * 16 + ni * 4 + kq)) * 512 + lane * 8;
            bh[ni] = *(const bf16x8*)(Wh + fb);
            bl[ni] = *(const bf16x8*)(Wl + fb);
        }
        bf16x8 ah[4], al[4];
#pragma unroll
        for (int mi = 0; mi < 4; ++mi) {
            ah[mi] = *(const bf16x8*)&a_h[buf][aoff[mi]];
            al[mi] = *(const bf16x8*)&a_l[buf][aoff[mi]];
        }
#pragma unroll
        for (int mi = 0; mi < 4; ++mi)
#pragma unroll
            for (int ni = 0; ni < 4; ++ni)
                acc[mi][ni] = __builtin_amdgcn_mfma_f32_16x16x32_bf16(
                    ah[mi], bh[ni], acc[mi][ni], 0, 0, 0);
#pragma unroll
        for (int mi = 0; mi < 4; ++mi)
#pragma unroll
            for (int ni = 0; ni < 4; ++ni)
                acc[mi][ni] = __builtin_amdgcn_mfma_f32_16x16x32_bf16(
                    al[mi], bh[ni], acc[mi][ni], 0, 0, 0);
#pragma unroll
        for (int mi = 0; mi < 4; ++mi)
#pragma unroll
            for (int ni = 0; ni < 4; ++ni)
                acc[mi][ni] = __builtin_amdgcn_mfma_f32_16x16x32_bf16(
                    ah[mi], bl[ni], acc[mi][ni], 0, 0, 0);

        if (kc + 1 < NKC) cvtstore(f, buf ^ 1);
        __syncthreads();
        buf ^= 1;
    }

    // epilogue: assemble i,f,g,o per (row,k) into one coalesced float4
    const int kcol = kq * 16 + (lane & 15);
    float bias4[4];
#pragma unroll
    for (int g = 0; g < 4; ++g)
        bias4[g] = bih[dir * 256 + g * 64 + kcol] + bhh[dir * 256 + g * 64 + kcol];
#pragma unroll
    for (int mi = 0; mi < 4; ++mi) {
        int mrow = m0 + wr * 64 + mi * 16 + ((lane >> 4) << 2);
#pragma unroll
        for (int r = 0; r < 4; ++r) {
            float4 v = make_float4(acc[mi][0][r] + bias4[0], acc[mi][1][r] + bias4[1],
                                   acc[mi][2][r] + bias4[2], acc[mi][3][r] + bias4[3]);
            *(float4*)&xg[((size_t)dir * MROWS + mrow + r) * 256 + kcol * 4] = v;
        }
    }
}

// ---------------------------------------------------------------------------
// LSTM recurrence v10 (unchanged): G=4, grid 512, lds_barrier, ping-pong
// prefetch registers (2x unrolled steps).
// ---------------------------------------------------------------------------
__global__ __launch_bounds__(256, 2) void lstm_rec_kernel(
    const float* __restrict__ xg,     // [2][NSEQ][T][64k][4g]
    const __bf16* __restrict__ whhf,  // [hi 32768 | lo 32768] frag-ordered
    float* __restrict__ out,
    int write_all)
{
    const int tid  = threadIdx.x;
    const int wv   = tid >> 6;        // wave 0..3 = k-slice
    const int lane = tid & 63;
    const int nl   = lane & 15;
    const int lq   = lane >> 4;

    const int bid  = blockIdx.x;      // grid 512
    const int dir  = bid & 1;
    const int seq0 = (bid >> 1) * 4;  // 4 seqs per block

    // B fragments: Whh' hi/lo, held in VGPRs for the whole kernel
    const __bf16* wh = whhf;
    const __bf16* wl = whhf + 32768;
    bf16x8 bh[2][4], bl[2][4];
#pragma unroll
    for (int kc = 0; kc < 2; ++kc)
#pragma unroll
        for (int g = 0; g < 4; ++g) {
            size_t fb = ((size_t)((dir * 2 + kc) * 16 + g * 4 + wv)) * 512 + lane * 8;
            bh[kc][g] = *(const bf16x8*)(wh + fb);
            bl[kc][g] = *(const bf16x8*)(wl + fb);
        }

    // h broadcast buffers: [parity][s(16)][k(64)] bf16, XOR-swizzled on k>>3
    __shared__ __align__(16) __bf16 h_hi[2048];
    __shared__ __align__(16) __bf16 h_lo[2048];
    {
        uint4 z = {0, 0, 0, 0};
        *(uint4*)&h_hi[tid * 8] = z;
        *(uint4*)&h_lo[tid * 8] = z;
    }

    const int k   = wv * 16 + nl;     // this lane's hidden index (cell phase)
    const int g8k = k >> 3;

    float c[4] = {0.0f, 0.0f, 0.0f, 0.0f};
    float4 xa[4] = {}, xb[4] = {};

    // stepping pointers
    const float* pxg = xg + (((size_t)dir * NSEQ + seq0) * TT
                             + (dir ? (TT - 1) : 0)) * 256 + k * 4;
    const int dstep = dir ? -256 : 256;
    float* pout = out + ((size_t)seq0 * TT + (dir ? (TT - 1) : 0)) * 128
                + dir * 64 + k;
    const int ostep = dir ? -128 : 128;

    auto load_xg = [&](float4 (&d)[4]) {
        if (lane < 16) {
#pragma unroll
            for (int r = 0; r < 4; ++r)
                d[r] = *(const float4*)(pxg + (size_t)r * TT * 256);
        }
        pxg += dstep;
    };

    int buf = 0;
    auto step_body = [&](int step, float4 (&xcur)[4], float4 (&xnext)[4], bool pre) {
        // A fragments: h(step) from LDS buf
        const int aof0 = buf * 1024 + nl * 64 + (((0 + lq) ^ (nl & 7)) * 8);
        const int aof1 = buf * 1024 + nl * 64 + (((4 + lq) ^ (nl & 7)) * 8);
        bf16x8 ah0 = *(const bf16x8*)&h_hi[aof0];
        bf16x8 ah1 = *(const bf16x8*)&h_hi[aof1];
        bf16x8 al0 = *(const bf16x8*)&h_lo[aof0];
        bf16x8 al1 = *(const bf16x8*)&h_lo[aof1];

        if (pre) load_xg(xnext);          // stays in flight a FULL step

        f32x4 acc[4];
#pragma unroll
        for (int g = 0; g < 4; ++g) acc[g] = (f32x4){0.0f, 0.0f, 0.0f, 0.0f};
#pragma unroll
        for (int g = 0; g < 4; ++g)
            acc[g] = __builtin_amdgcn_mfma_f32_16x16x32_bf16(ah0, bh[0][g], acc[g], 0, 0, 0);
#pragma unroll
        for (int g = 0; g < 4; ++g)
            acc[g] = __builtin_amdgcn_mfma_f32_16x16x32_bf16(ah1, bh[1][g], acc[g], 0, 0, 0);
#pragma unroll
        for (int g = 0; g < 4; ++g)
            acc[g] = __builtin_amdgcn_mfma_f32_16x16x32_bf16(al0, bh[0][g], acc[g], 0, 0, 0);
#pragma unroll
        for (int g = 0; g < 4; ++g)
            acc[g] = __builtin_amdgcn_mfma_f32_16x16x32_bf16(al1, bh[1][g], acc[g], 0, 0, 0);
#pragma unroll
        for (int g = 0; g < 4; ++g)
            acc[g] = __builtin_amdgcn_mfma_f32_16x16x32_bf16(ah0, bl[0][g], acc[g], 0, 0, 0);
#pragma unroll
        for (int g = 0; g < 4; ++g)
            acc[g] = __builtin_amdgcn_mfma_f32_16x16x32_bf16(ah1, bl[1][g], acc[g], 0, 0, 0);

        if (lane < 16) {
            // seqs 0..3 in acc rows 0..3 (lq==0 lanes)
#pragma unroll
            for (int r = 0; r < 4; ++r) {
                float iv = sigmoid_f(acc[0][r] + xcur[r].x);
                float fv = sigmoid_f(acc[1][r] + xcur[r].y);
                float gv = tanh_f  (acc[2][r] + xcur[r].z);
                float ov = sigmoid_f(acc[3][r] + xcur[r].w);
                c[r] = fv * c[r] + iv * gv;
                float h = ov * tanh_f(c[r]);
                int off = (buf ^ 1) * 1024 + r * 64 + ((g8k ^ r) * 8) + (k & 7);
                __bf16 hh = bfh(h);
                h_hi[off] = hh;
                h_lo[off] = bfh(h - bf2f(hh));
                if (write_all)
                    pout[(size_t)r * TT * 128] = h;
                else if (step == TT - 1)
                    out[(size_t)(seq0 + r) * 128 + dir * 64 + k] = h;
            }
        }
        pout += ostep;
        lds_barrier();
        buf ^= 1;
    };

    load_xg(xa);                           // t=0
    lds_barrier();

    for (int step = 0; step < TT; step += 2) {
        step_body(step,     xa, xb, true);             // consume xa, fetch t+1
        step_body(step + 1, xb, xa, step + 2 < TT);    // consume xb, fetch t+2
    }
}

// ---------------------------------------------------------------------------
__global__ __launch_bounds__(256) void fc_kernel(
    const float* __restrict__ fin,   // [NSEQ][128]
    const float* __restrict__ fc_W,  // [128]
    const float* __restrict__ fc_b,  // [1]
    float* __restrict__ outp)        // [NSEQ]
{
    int s = blockIdx.x * 256 + threadIdx.x;
    const float* fr = fin + (size_t)s * 128;
    float acc = fc_b[0];
#pragma unroll
    for (int k4 = 0; k4 < 32; ++k4) {
        float4 fv = *(const float4*)&fr[k4 * 4];
        float4 wv2 = *(const float4*)&fc_W[k4 * 4];
        acc += fv.x * wv2.x + fv.y * wv2.y + fv.z * wv2.z + fv.w * wv2.w;
    }
    outp[s] = acc;
}

// ---------------------------------------------------------------------------
extern "C" void kernel_launch(void* const* d_in, const int* in_sizes, int n_in,
                              void* d_out, int out_size, void* d_ws, size_t ws_size,
                              hipStream_t stream) {
    const float* x       = (const float*)d_in[0];
    const float* adj     = (const float*)d_in[1];
    const float* gat0_W  = (const float*)d_in[2];
    const float* gat0_a  = (const float*)d_in[3];
    const float* gat0_g  = (const float*)d_in[4];
    const float* gat0_b  = (const float*)d_in[5];
    const float* gat1_W  = (const float*)d_in[6];
    const float* gat1_a  = (const float*)d_in[7];
    const float* gat1_g  = (const float*)d_in[8];
    const float* gat1_b  = (const float*)d_in[9];
    const float* res_W   = (const float*)d_in[10];
    const float* res_b   = (const float*)d_in[11];
    const float* alpha_g = (const float*)d_in[12];
    const float* l0_Wih  = (const float*)d_in[13];
    const float* l0_Whh  = (const float*)d_in[14];
    const float* l0_bih  = (const float*)d_in[15];
    const float* l0_bhh  = (const float*)d_in[16];
    const float* l1_Wih  = (const float*)d_in[17];
    const float* l1_Whh  = (const float*)d_in[18];
    const float* l1_bih  = (const float*)d_in[19];
    const float* l1_bhh  = (const float*)d_in[20];
    const float* fc_W    = (const float*)d_in[21];
    const float* fc_b    = (const float*)d_in[22];

    float* ws = (float*)d_ws;
    float* g0    = ws;                    // [M][N][64]
    float* g1    = ws + 4194304;          // [M][N][64]
    float* seq   = ws + 8388608;          // [B*N][T][64]
    float* xg    = ws + 12582912;         // [2][65536][256]
    float* fin   = ws + 46137344;         // [NSEQ][128]
    float* o1    = ws;                    // reuse g0+g1 [NSEQ][T][128]

    // Wih' (bf16 hi/lo, frag-ordered) OVERLAPS fin: lifetimes disjoint
    __bf16* w0h = (__bf16*)(ws + 46137344);
    __bf16* w0l = w0h + 2 * 64 * 256;
    __bf16* w1h = w0l + 2 * 64 * 256;
    __bf16* w1l = w1h + 2 * 128 * 256;

    // Whh' frags live in the seq region (dead after xg_mfma<64>)
    __bf16* whhf = (__bf16*)seq;          // [2 layers][hi 32768 | lo 32768]

    wcvt_kernel<64><<<128, 256, 0, stream>>>(l0_Wih, w0h, w0l);
    wcvt_kernel<128><<<256, 256, 0, stream>>>(l1_Wih, w1h, w1l);
    gat_kernel<32><<<MM, 256, 0, stream>>>(x, adj, gat0_W, gat0_a, gat0_g, gat0_b, g0);
    gat_kernel<64><<<MM, 256, 0, stream>>>(g0, adj, gat1_W, gat1_a, gat1_g, gat1_b, g1);
    combine_kernel<<<(BB*SS*NN)/4, 256, 0, stream>>>(x, g1, res_W, res_b, alpha_g, seq);
    xg_mfma_kernel<64><<<2048, 256, 0, stream>>>(seq, w0h, w0l, l0_bih, l0_bhh, xg);
    whhcvt_kernel<<<256, 256, 0, stream>>>(l0_Whh, l1_Whh, whhf);
    lstm_rec_kernel<<<512, 256, 0, stream>>>(xg, whhf, o1, 1);
    xg_mfma_kernel<128><<<2048, 256, 0, stream>>>(o1, w1h, w1l, l1_bih, l1_bhh, xg);
    lstm_rec_kernel<<<512, 256, 0, stream>>>(xg, whhf + 65536, fin, 0);
    fc_kernel<<<NSEQ/256, 256, 0, stream>>>(fin, fc_W, fc_b, (float*)d_out);
}

// Round 14
// 470.561 us; speedup vs baseline: 1.2345x; 1.1303x over previous
//
#include <hip/hip_runtime.h>
#include <math.h>

// Problem constants
#define BB 4
#define SS 64
#define NN 256
#define FF 32
#define HH 64
#define MM (BB*SS)      // 256 graphs
#define NSEQ (BB*NN)    // 1024 sequences
#define TT SS           // 64 timesteps
#define MROWS (NSEQ*TT) // 65536 GEMM rows

// fast activations: v_rcp_f32 (~1ulp) instead of IEEE divide
__device__ __forceinline__ float fast_rcp(float x) { return __builtin_amdgcn_rcpf(x); }
__device__ __forceinline__ float sigmoid_f(float x) { return fast_rcp(1.0f + __expf(-x)); }
__device__ __forceinline__ float tanh_f(float x) {
    float t = __expf(-2.0f * fabsf(x));
    float r = (1.0f - t) * fast_rcp(1.0f + t);
    return copysignf(r, x);
}

// LDS-only barrier: waits ONLY lgkmcnt (LDS) before s_barrier, leaving global
// prefetch loads / stores IN FLIGHT across the barrier.
// sched_barrier(0) pins post-barrier ds_reads (guide rule #18).
__device__ __forceinline__ void lds_barrier() {
    asm volatile("s_waitcnt lgkmcnt(0)" ::: "memory");
    __builtin_amdgcn_s_barrier();
    __builtin_amdgcn_sched_barrier(0);
}

// ---- bf16 split helpers (RTNE hi, hi+lo captures ~17 mantissa bits) ----
typedef __bf16 bf16x8 __attribute__((ext_vector_type(8)));
typedef float  f32x4  __attribute__((ext_vector_type(4)));

__device__ __forceinline__ __bf16 bfh(float x) {
    unsigned u = __float_as_uint(x);
    unsigned r = (u + 0x7FFFu + ((u >> 16) & 1u)) >> 16;
    return __builtin_bit_cast(__bf16, (unsigned short)r);
}
__device__ __forceinline__ float bf2f(__bf16 b) {
    unsigned u = ((unsigned)__builtin_bit_cast(unsigned short, b)) << 16;
    return __uint_as_float(u);
}

// ---------------------------------------------------------------------------
// GAT layer v3 (unchanged from r13): MFMA aggregation.
// ---------------------------------------------------------------------------
template<int FIN>
__global__ __launch_bounds__(256) void gat_kernel(
    const float* __restrict__ xin,   // [M][N][FIN]
    const float* __restrict__ adj,   // [M][N][N]
    const float* __restrict__ W,     // [FIN][64]
    const float* __restrict__ a,     // [128]
    const float* __restrict__ gamma_, const float* __restrict__ beta_,
    float* __restrict__ gout)        // [M][N][64]
{
    __shared__ __align__(16) float u_f32[256 * 68];     // 69632 B, reused as F
    __shared__ __align__(16) __bf16 p_hi[256 * 40];     // 20480 B
    __shared__ __align__(16) __bf16 p_lo[256 * 40];
    __shared__ float s1s[256], s2s[256], srow[256];

    __bf16* F_hi = (__bf16*)u_f32;          // [64][264] bf16 (33792 B)
    __bf16* F_lo = F_hi + 64 * 264;         // (+33792 B <= 69632) OK

    const int m    = blockIdx.x;
    const int tid  = threadIdx.x;
    const int lane = tid & 63;
    const int wv   = tid >> 6;
    const int nl   = lane & 15;
    const int lq   = lane >> 4;

    // ---- Phase A: h = x @ W -> U (fp32, stride 68) ----
    {
        const int c = tid & 63;
        const int w = tid >> 6;
        float wreg[FIN];
#pragma unroll
        for (int f = 0; f < FIN; ++f) wreg[f] = W[f * 64 + c];
        const float* xm = xin + (size_t)m * NN * FIN;
        for (int i0 = 0; i0 < 64; ++i0) {
            int i = (i0 << 2) | w;
            float acc = 0.0f;
#pragma unroll
            for (int f4 = 0; f4 < FIN / 4; ++f4) {
                float4 xv = *(const float4*)&xm[i * FIN + f4 * 4];
                acc += xv.x * wreg[f4*4] + xv.y * wreg[f4*4+1]
                     + xv.z * wreg[f4*4+2] + xv.w * wreg[f4*4+3];
            }
            u_f32[i * 68 + c] = acc;
        }
    }
    __syncthreads();

    // ---- Conversion: row tid -> regs; s1/s2; then U reused as F (bf16) ----
    float hr[64];
    {
        const float* hp = &u_f32[tid * 68];
        float acc1 = 0.0f, acc2 = 0.0f;
#pragma unroll
        for (int c4 = 0; c4 < 16; ++c4) {
            float4 hv = *(const float4*)&hp[c4 * 4];
            hr[c4*4+0] = hv.x; hr[c4*4+1] = hv.y; hr[c4*4+2] = hv.z; hr[c4*4+3] = hv.w;
            float4 av1 = *(const float4*)&a[c4 * 4];
            float4 av2 = *(const float4*)&a[64 + c4 * 4];
            acc1 += hv.x * av1.x + hv.y * av1.y + hv.z * av1.z + hv.w * av1.w;
            acc2 += hv.x * av2.x + hv.y * av2.y + hv.z * av2.z + hv.w * av2.w;
        }
        s1s[tid] = acc1; s2s[tid] = acc2;
    }
    __syncthreads();                       // ALL U reads done before overwrite
    {
#pragma unroll
        for (int c = 0; c < 64; ++c) {
            __bf16 hh = bfh(hr[c]);
            F_hi[c * 264 + tid] = hh;
            F_lo[c * 264 + tid] = bfh(hr[c] - bf2f(hh));
        }
    }

    // ---- chunk loop: p staging + MFMA ----
    const float* adjr = adj + ((size_t)m * NN + tid) * NN;
    const float s1v = s1s[tid];
    float srow_acc = 0.0f;

    f32x4 acc[4][4];
#pragma unroll
    for (int mt = 0; mt < 4; ++mt)
#pragma unroll
        for (int nt = 0; nt < 4; ++nt)
            acc[mt][nt] = (f32x4){0.0f, 0.0f, 0.0f, 0.0f};

    float4 adjreg[8];
#pragma unroll
    for (int q = 0; q < 8; ++q) adjreg[q] = *(const float4*)&adjr[q * 4];

    for (int ch = 0; ch < 8; ++ch) {
        // make_p: 32 unnormalized attention weights for row tid
        {
            float pv[32];
#pragma unroll
            for (int q = 0; q < 8; ++q) {
                float4 av = adjreg[q];
                float4 sv = *(const float4*)&s2s[ch * 32 + q * 4];
                float e0 = s1v + sv.x, e1 = s1v + sv.y, e2 = s1v + sv.z, e3 = s1v + sv.w;
                e0 = (e0 > 0.0f) ? e0 : 0.2f * e0;
                e1 = (e1 > 0.0f) ? e1 : 0.2f * e1;
                e2 = (e2 > 0.0f) ? e2 : 0.2f * e2;
                e3 = (e3 > 0.0f) ? e3 : 0.2f * e3;
                float p0 = (av.x > 0.0f) ? __expf(e0) : 0.0f;
                float p1 = (av.y > 0.0f) ? __expf(e1) : 0.0f;
                float p2 = (av.z > 0.0f) ? __expf(e2) : 0.0f;
                float p3 = (av.w > 0.0f) ? __expf(e3) : 0.0f;
                srow_acc += (p0 + p1) + (p2 + p3);
                pv[q*4+0] = p0; pv[q*4+1] = p1; pv[q*4+2] = p2; pv[q*4+3] = p3;
            }
#pragma unroll
            for (int b = 0; b < 4; ++b) {
                bf16x8 h8, l8;
#pragma unroll
                for (int j = 0; j < 8; ++j) {
                    __bf16 hh = bfh(pv[b*8+j]);
                    h8[j] = hh;
                    l8[j] = bfh(pv[b*8+j] - bf2f(hh));
                }
                *(bf16x8*)&p_hi[tid * 40 + b * 8] = h8;
                *(bf16x8*)&p_lo[tid * 40 + b * 8] = l8;
            }
        }
        if (ch < 7) {                     // prefetch next adj chunk (in flight)
#pragma unroll
            for (int q = 0; q < 8; ++q)
                adjreg[q] = *(const float4*)&adjr[(ch + 1) * 32 + q * 4];
        }
        lds_barrier();                    // p (and F, first iter) visible

        // MFMA: wave wv owns rows [wv*64, wv*64+64)
        bf16x8 pah[4], pal[4], fbh[4], fbl[4];
#pragma unroll
        for (int mt = 0; mt < 4; ++mt) {
            int row = wv * 64 + mt * 16 + nl;
            pah[mt] = *(const bf16x8*)&p_hi[row * 40 + lq * 8];
            pal[mt] = *(const bf16x8*)&p_lo[row * 40 + lq * 8];
        }
#pragma unroll
        for (int nt = 0; nt < 4; ++nt) {
            int fo = (nt * 16 + nl) * 264 + ch * 32 + lq * 8;
            fbh[nt] = *(const bf16x8*)&F_hi[fo];
            fbl[nt] = *(const bf16x8*)&F_lo[fo];
        }
#pragma unroll
        for (int mt = 0; mt < 4; ++mt)
#pragma unroll
            for (int nt = 0; nt < 4; ++nt)
                acc[mt][nt] = __builtin_amdgcn_mfma_f32_16x16x32_bf16(
                    pah[mt], fbh[nt], acc[mt][nt], 0, 0, 0);
#pragma unroll
        for (int mt = 0; mt < 4; ++mt)
#pragma unroll
            for (int nt = 0; nt < 4; ++nt)
                acc[mt][nt] = __builtin_amdgcn_mfma_f32_16x16x32_bf16(
                    pal[mt], fbh[nt], acc[mt][nt], 0, 0, 0);
#pragma unroll
        for (int mt = 0; mt < 4; ++mt)
#pragma unroll
            for (int nt = 0; nt < 4; ++nt)
                acc[mt][nt] = __builtin_amdgcn_mfma_f32_16x16x32_bf16(
                    pah[mt], fbl[nt], acc[mt][nt], 0, 0, 0);

        lds_barrier();                    // MFMA reads done before p overwrite
    }

    srow[tid] = srow_acc;
    __syncthreads();

    // ---- epilogue: normalize, LN over 64 cols (shfl over nl bits), ELU ----
    float gm[4], bt[4];
#pragma unroll
    for (int nt = 0; nt < 4; ++nt) {
        gm[nt] = gamma_[nt * 16 + nl];
        bt[nt] = beta_[nt * 16 + nl];
    }
#pragma unroll
    for (int mt = 0; mt < 4; ++mt) {
#pragma unroll
        for (int r = 0; r < 4; ++r) {
            int row = wv * 64 + mt * 16 + lq * 4 + r;
            float rinv = fast_rcp(srow[row]);
            float v[4];
            float sm = 0.0f, sq = 0.0f;
#pragma unroll
            for (int nt = 0; nt < 4; ++nt) {
                v[nt] = acc[mt][nt][r] * rinv;
                sm += v[nt]; sq += v[nt] * v[nt];
            }
#pragma unroll
            for (int off = 1; off < 16; off <<= 1) {
                sm += __shfl_xor(sm, off);
                sq += __shfl_xor(sq, off);
            }
            float mu  = sm * (1.0f / 64.0f);
            float var = sq * (1.0f / 64.0f) - mu * mu;
            float rs  = rsqrtf(var + 1e-5f);
            float* gp = &gout[((size_t)m * NN + row) * 64];
#pragma unroll
            for (int nt = 0; nt < 4; ++nt) {
                float hn = (v[nt] - mu) * rs * gm[nt] + bt[nt];
                gp[nt * 16 + nl] = (hn > 0.0f) ? hn : (__expf(hn) - 1.0f);
            }
        }
    }
}

// ---------------------------------------------------------------------------
// residual + gate*g, reshaped to sequence layout [B*N][T][H] (unchanged)
// ---------------------------------------------------------------------------
__global__ __launch_bounds__(256) void combine_kernel(
    const float* __restrict__ x,      // [B*S*N][32]
    const float* __restrict__ g1,     // [B*S*N][64]
    const float* __restrict__ res_W,  // [32][64]
    const float* __restrict__ res_b,  // [64]
    const float* __restrict__ alpha_p,
    float* __restrict__ seqout)       // [B*N][T][64]
{
    int row = blockIdx.x * 4 + (threadIdx.x >> 6);
    int h = threadIdx.x & 63;
    int mg = row >> 8, n = row & 255;
    int b = mg >> 6, s = mg & 63;
    const float* xr = x + (size_t)row * 32;
    float acc = res_b[h];
#pragma unroll
    for (int f4 = 0; f4 < 8; ++f4) {
        float4 xv = *(const float4*)&xr[f4 * 4];
        acc += xv.x * res_W[(f4*4    ) * 64 + h] + xv.y * res_W[(f4*4 + 1) * 64 + h]
             + xv.z * res_W[(f4*4 + 2) * 64 + h] + xv.w * res_W[(f4*4 + 3) * 64 + h];
    }
    float alpha = fminf(fmaxf(alpha_p[0], 0.0f), 1.0f);
    acc += alpha * g1[(size_t)row * 64 + h];
    seqout[(((size_t)(b * NN + n)) * TT + s) * 64 + h] = acc;
}

// ---------------------------------------------------------------------------
// W pre-convert: Wih[2][K][256] fp32 -> fragment-ordered bf16 hi/lo.
// ---------------------------------------------------------------------------
template<int K>
__global__ __launch_bounds__(256) void wcvt_kernel(
    const float* __restrict__ Wih, __bf16* __restrict__ Wh, __bf16* __restrict__ Wl)
{
    constexpr int NKC = K / 32;
    int idx = blockIdx.x * 256 + threadIdx.x;
    int j   = idx & 7;
    int nl  = (idx >> 3) & 15;
    int g   = (idx >> 7) & 3;
    int ng  = (idx >> 9) & 15;
    int rest = idx >> 13;                 // dir*NKC + kc
    int kc  = rest & (NKC - 1);
    int dir = rest / NKC;
    int k = kc * 32 + g * 8 + j;
    int n = ng * 16 + nl;
    float x = Wih[((size_t)dir * K + k) * 256 + n];
    __bf16 h = bfh(x);
    Wh[idx] = h;
    Wl[idx] = bfh(x - bf2f(h));
}

// ---------------------------------------------------------------------------
// Whh pre-convert (both layers, one launch): same frag layout as wcvt<64>.
// ---------------------------------------------------------------------------
__global__ __launch_bounds__(256) void whhcvt_kernel(
    const float* __restrict__ W0, const float* __restrict__ W1,
    __bf16* __restrict__ outw)
{
    int idx = blockIdx.x * 256 + threadIdx.x;   // 0..65535
    int lay = idx >> 15;
    int r   = idx & 32767;
    int j   = r & 7;
    int nl  = (r >> 3) & 15;
    int g   = (r >> 7) & 3;
    int ng  = (r >> 9) & 15;
    int rest = r >> 13;                  // dir*2 + kc
    int kc  = rest & 1;
    int dir = rest >> 1;
    int k = kc * 32 + g * 8 + j;
    int n = ng * 16 + nl;
    const float* W = lay ? W1 : W0;
    float x = W[((size_t)dir * 64 + k) * 256 + n];
    __bf16 h = bfh(x);
    outw[lay * 65536 + r]         = h;
    outw[lay * 65536 + 32768 + r] = bfh(x - bf2f(h));
}

// ---------------------------------------------------------------------------
// xg GEMM via split-bf16 MFMA — gate-grouped wave columns, coalesced float4
// epilogue into [k][gate] layout. NOW with lds_barrier (not __syncthreads):
// the A-prefetch global loads stay in flight across the per-chunk barrier
// (the vmcnt(0) drain was serially exposing HBM latency per K-chunk —
// same defect fixed in the lstm at r11, measured −8%).
// ---------------------------------------------------------------------------
template<int K>
__global__ __launch_bounds__(256, 2) void xg_mfma_kernel(
    const float* __restrict__ A,       // [MROWS][K]
    const __bf16* __restrict__ Wh,     // frag-ordered
    const __bf16* __restrict__ Wl,
    const float* __restrict__ bih,     // [2][256]
    const float* __restrict__ bhh,     // [2][256]
    float* __restrict__ xg)            // [2][MROWS][64k][4g]
{
    constexpr int NKC = K / 32;
    __shared__ __bf16 a_h[2][128 * 32];
    __shared__ __bf16 a_l[2][128 * 32];

    const int tid  = threadIdx.x;
    const int lane = tid & 63;
    const int w    = tid >> 6;
    const int wr   = w >> 1, wc = w & 1;

    int bid = blockIdx.x;
    int wg  = (bid >> 3) | ((bid & 7) << 8);
    int cd  = wg & 3;
    int m0  = (wg >> 2) * 128;
    int dir = cd >> 1;
    const int kq = (cd & 1) * 2 + wc;    // wave's 16-k group (0..3)

    f32x4 acc[4][4];
#pragma unroll
    for (int mi = 0; mi < 4; ++mi)
#pragma unroll
        for (int ni = 0; ni < 4; ++ni)
            acc[mi][ni] = (f32x4){0.0f, 0.0f, 0.0f, 0.0f};

    const int srow = tid >> 1;
    const int g0   = (tid & 1) * 2;
    const float* abase = A + (size_t)(m0 + srow) * K + (tid & 1) * 16;
    const int soff0 = srow * 32 + (( g0      ^ (srow & 3)) * 8);
    const int soff1 = srow * 32 + (((g0 + 1) ^ (srow & 3)) * 8);

    int aoff[4];
#pragma unroll
    for (int mi = 0; mi < 4; ++mi)
        aoff[mi] = (wr * 64 + mi * 16 + (lane & 15)) * 32
                 + (((lane >> 4) ^ (lane & 3)) * 8);

    auto cvtstore = [&](const float* f, int buf) {
        bf16x8 h0, h1, l0, l1;
#pragma unroll
        for (int i = 0; i < 8; ++i) {
            __bf16 ha = bfh(f[i]);
            __bf16 hb = bfh(f[8 + i]);
            h0[i] = ha; l0[i] = bfh(f[i]     - bf2f(ha));
            h1[i] = hb; l1[i] = bfh(f[8 + i] - bf2f(hb));
        }
        *(bf16x8*)&a_h[buf][soff0] = h0;
        *(bf16x8*)&a_h[buf][soff1] = h1;
        *(bf16x8*)&a_l[buf][soff0] = l0;
        *(bf16x8*)&a_l[buf][soff1] = l1;
    };

    {
        float f[16];
#pragma unroll
        for (int i = 0; i < 4; ++i) {
            float4 v = *(const float4*)(abase + i * 4);
            f[i*4+0] = v.x; f[i*4+1] = v.y; f[i*4+2] = v.z; f[i*4+3] = v.w;
        }
        cvtstore(f, 0);
    }
    lds_barrier();

    int buf = 0;
    for (int kc = 0; kc < NKC; ++kc) {
        float f[16];
        if (kc + 1 < NKC) {
#pragma unroll
            for (int i = 0; i < 4; ++i) {
                float4 v = *(const float4*)(abase + (kc + 1) * 32 + i * 4);
                f[i*4+0] = v.x; f[i*4+1] = v.y; f[i*4+2] = v.z; f[i*4+3] = v.w;
            }
        }
        bf16x8 bh[4], bl[4];
#pragma unroll
        for (int ni = 0; ni < 4; ++ni) {   // ni = gate
            size_t fb = ((size_t)((dir * NKC + kc) * 16 + ni * 4 + kq)) * 512 + lane * 8;
            bh[ni] = *(const bf16x8*)(Wh + fb);
            bl[ni] = *(const bf16x8*)(Wl + fb);
        }
        bf16x8 ah[4], al[4];
#pragma unroll
        for (int mi = 0; mi < 4; ++mi) {
            ah[mi] = *(const bf16x8*)&a_h[buf][aoff[mi]];
            al[mi] = *(const bf16x8*)&a_l[buf][aoff[mi]];
        }
#pragma unroll
        for (int mi = 0; mi < 4; ++mi)
#pragma unroll
            for (int ni = 0; ni < 4; ++ni)
                acc[mi][ni] = __builtin_amdgcn_mfma_f32_16x16x32_bf16(
                    ah[mi], bh[ni], acc[mi][ni], 0, 0, 0);
#pragma unroll
        for (int mi = 0; mi < 4; ++mi)
#pragma unroll
            for (int ni = 0; ni < 4; ++ni)
                acc[mi][ni] = __builtin_amdgcn_mfma_f32_16x16x32_bf16(
                    al[mi], bh[ni], acc[mi][ni], 0, 0, 0);
#pragma unroll
        for (int mi = 0; mi < 4; ++mi)
#pragma unroll
            for (int ni = 0; ni < 4; ++ni)
                acc[mi][ni] = __builtin_amdgcn_mfma_f32_16x16x32_bf16(
                    ah[mi], bl[ni], acc[mi][ni], 0, 0, 0);

        if (kc + 1 < NKC) cvtstore(f, buf ^ 1);
        lds_barrier();
        buf ^= 1;
    }

    // epilogue: assemble i,f,g,o per (row,k) into one coalesced float4
    const int kcol = kq * 16 + (lane & 15);
    float bias4[4];
#pragma unroll
    for (int g = 0; g < 4; ++g)
        bias4[g] = bih[dir * 256 + g * 64 + kcol] + bhh[dir * 256 + g * 64 + kcol];
#pragma unroll
    for (int mi = 0; mi < 4; ++mi) {
        int mrow = m0 + wr * 64 + mi * 16 + ((lane >> 4) << 2);
#pragma unroll
        for (int r = 0; r < 4; ++r) {
            float4 v = make_float4(acc[mi][0][r] + bias4[0], acc[mi][1][r] + bias4[1],
                                   acc[mi][2][r] + bias4[2], acc[mi][3][r] + bias4[3]);
            *(float4*)&xg[((size_t)dir * MROWS + mrow + r) * 256 + kcol * 4] = v;
        }
    }
}

// ---------------------------------------------------------------------------
// LSTM recurrence v11 = v10 + all-64-lane cell phase.
// v10's cell phase ran on lanes<16 with 4 cells/lane (4x trans-op issue,
// 48 lanes idle). Redistribute acc via shfl so each of the 64 lanes owns ONE
// cell (s=lq, k=wv*16+nl): act op count /4, c-state 4->1 VGPR, xg regs
// 4xfloat4 -> 1, wider-coalesced out/LDS writes. Identical math.
// ---------------------------------------------------------------------------
__global__ __launch_bounds__(256, 2) void lstm_rec_kernel(
    const float* __restrict__ xg,     // [2][NSEQ][T][64k][4g]
    const __bf16* __restrict__ whhf,  // [hi 32768 | lo 32768] frag-ordered
    float* __restrict__ out,
    int write_all)
{
    const int tid  = threadIdx.x;
    const int wv   = tid >> 6;        // wave 0..3 = k-slice
    const int lane = tid & 63;
    const int nl   = lane & 15;
    const int lq   = lane >> 4;       // = this lane's seq (cell phase)

    const int bid  = blockIdx.x;      // grid 512
    const int dir  = bid & 1;
    const int seq0 = (bid >> 1) * 4;  // 4 seqs per block

    // B fragments: Whh' hi/lo, held in VGPRs for the whole kernel
    const __bf16* wh = whhf;
    const __bf16* wl = whhf + 32768;
    bf16x8 bh[2][4], bl[2][4];
#pragma unroll
    for (int kc = 0; kc < 2; ++kc)
#pragma unroll
        for (int g = 0; g < 4; ++g) {
            size_t fb = ((size_t)((dir * 2 + kc) * 16 + g * 4 + wv)) * 512 + lane * 8;
            bh[kc][g] = *(const bf16x8*)(wh + fb);
            bl[kc][g] = *(const bf16x8*)(wl + fb);
        }

    // h broadcast buffers: [parity][s(16)][k(64)] bf16, XOR-swizzled on k>>3
    __shared__ __align__(16) __bf16 h_hi[2048];
    __shared__ __align__(16) __bf16 h_lo[2048];
    {
        uint4 z = {0, 0, 0, 0};
        *(uint4*)&h_hi[tid * 8] = z;
        *(uint4*)&h_lo[tid * 8] = z;
    }

    const int k   = wv * 16 + nl;     // this lane's hidden index (cell phase)
    const int g8k = k >> 3;

    float c = 0.0f;                   // ONE cell per lane
    float4 xa = {}, xb = {};

    // stepping pointers: lane loads the float4 (all 4 gates) for (seq0+lq, k)
    const float* pxg = xg + (((size_t)dir * NSEQ + seq0 + lq) * TT
                             + (dir ? (TT - 1) : 0)) * 256 + k * 4;
    const int dstep = dir ? -256 : 256;
    float* pout = out + (((size_t)(seq0 + lq)) * TT + (dir ? (TT - 1) : 0)) * 128
                + dir * 64 + k;
    const int ostep = dir ? -128 : 128;

    auto load_xg = [&](float4& d) {
        d = *(const float4*)pxg;
        pxg += dstep;
    };

    int buf = 0;
    auto step_body = [&](int step, float4& xcur, float4& xnext, bool pre) {
        // A fragments: h(step) from LDS buf
        const int aof0 = buf * 1024 + nl * 64 + (((0 + lq) ^ (nl & 7)) * 8);
        const int aof1 = buf * 1024 + nl * 64 + (((4 + lq) ^ (nl & 7)) * 8);
        bf16x8 ah0 = *(const bf16x8*)&h_hi[aof0];
        bf16x8 ah1 = *(const bf16x8*)&h_hi[aof1];
        bf16x8 al0 = *(const bf16x8*)&h_lo[aof0];
        bf16x8 al1 = *(const bf16x8*)&h_lo[aof1];

        if (pre) load_xg(xnext);          // stays in flight a FULL step

        f32x4 acc[4];
#pragma unroll
        for (int g = 0; g < 4; ++g) acc[g] = (f32x4){0.0f, 0.0f, 0.0f, 0.0f};
#pragma unroll
        for (int g = 0; g < 4; ++g)
            acc[g] = __builtin_amdgcn_mfma_f32_16x16x32_bf16(ah0, bh[0][g], acc[g], 0, 0, 0);
#pragma unroll
        for (int g = 0; g < 4; ++g)
            acc[g] = __builtin_amdgcn_mfma_f32_16x16x32_bf16(ah1, bh[1][g], acc[g], 0, 0, 0);
#pragma unroll
        for (int g = 0; g < 4; ++g)
            acc[g] = __builtin_amdgcn_mfma_f32_16x16x32_bf16(al0, bh[0][g], acc[g], 0, 0, 0);
#pragma unroll
        for (int g = 0; g < 4; ++g)
            acc[g] = __builtin_amdgcn_mfma_f32_16x16x32_bf16(al1, bh[1][g], acc[g], 0, 0, 0);
#pragma unroll
        for (int g = 0; g < 4; ++g)
            acc[g] = __builtin_amdgcn_mfma_f32_16x16x32_bf16(ah0, bl[0][g], acc[g], 0, 0, 0);
#pragma unroll
        for (int g = 0; g < 4; ++g)
            acc[g] = __builtin_amdgcn_mfma_f32_16x16x32_bf16(ah1, bl[1][g], acc[g], 0, 0, 0);

        // redistribute: lane (lq,nl) takes acc[g][r=lq] from lane nl
        float pre4[4];
#pragma unroll
        for (int g = 0; g < 4; ++g) {
            float b0 = __shfl(acc[g][0], nl);
            float b1 = __shfl(acc[g][1], nl);
            float b2 = __shfl(acc[g][2], nl);
            float b3 = __shfl(acc[g][3], nl);
            float v01 = (lq & 1) ? b1 : b0;
            float v23 = (lq & 1) ? b3 : b2;
            pre4[g] = (lq & 2) ? v23 : v01;
        }

        // cell update: ONE cell per lane (s = lq, k)
        float iv = sigmoid_f(pre4[0] + xcur.x);
        float fv = sigmoid_f(pre4[1] + xcur.y);
        float gv = tanh_f  (pre4[2] + xcur.z);
        float ov = sigmoid_f(pre4[3] + xcur.w);
        c = fv * c + iv * gv;
        float h = ov * tanh_f(c);
        int off = (buf ^ 1) * 1024 + lq * 64 + ((g8k ^ lq) * 8) + (k & 7);
        __bf16 hh = bfh(h);
        h_hi[off] = hh;
        h_lo[off] = bfh(h - bf2f(hh));
        if (write_all)
            pout[0] = h;
        else if (step == TT - 1)
            out[(size_t)(seq0 + lq) * 128 + dir * 64 + k] = h;
        pout += ostep;
        lds_barrier();
        buf ^= 1;
    };

    load_xg(xa);                           // t=0
    lds_barrier();

    for (int step = 0; step < TT; step += 2) {
        step_body(step,     xa, xb, true);             // consume xa, fetch t+1
        step_body(step + 1, xb, xa, step + 2 < TT);    // consume xb, fetch t+2
    }
}

// ---------------------------------------------------------------------------
__global__ __launch_bounds__(256) void fc_kernel(
    const float* __restrict__ fin,   // [NSEQ][128]
    const float* __restrict__ fc_W,  // [128]
    const float* __restrict__ fc_b,  // [1]
    float* __restrict__ outp)        // [NSEQ]
{
    int s = blockIdx.x * 256 + threadIdx.x;
    const float* fr = fin + (size_t)s * 128;
    float acc = fc_b[0];
#pragma unroll
    for (int k4 = 0; k4 < 32; ++k4) {
        float4 fv = *(const float4*)&fr[k4 * 4];
        float4 wv2 = *(const float4*)&fc_W[k4 * 4];
        acc += fv.x * wv2.x + fv.y * wv2.y + fv.z * wv2.z + fv.w * wv2.w;
    }
    outp[s] = acc;
}

// ---------------------------------------------------------------------------
extern "C" void kernel_launch(void* const* d_in, const int* in_sizes, int n_in,
                              void* d_out, int out_size, void* d_ws, size_t ws_size,
                              hipStream_t stream) {
    const float* x       = (const float*)d_in[0];
    const float* adj     = (const float*)d_in[1];
    const float* gat0_W  = (const float*)d_in[2];
    const float* gat0_a  = (const float*)d_in[3];
    const float* gat0_g  = (const float*)d_in[4];
    const float* gat0_b  = (const float*)d_in[5];
    const float* gat1_W  = (const float*)d_in[6];
    const float* gat1_a  = (const float*)d_in[7];
    const float* gat1_g  = (const float*)d_in[8];
    const float* gat1_b  = (const float*)d_in[9];
    const float* res_W   = (const float*)d_in[10];
    const float* res_b   = (const float*)d_in[11];
    const float* alpha_g = (const float*)d_in[12];
    const float* l0_Wih  = (const float*)d_in[13];
    const float* l0_Whh  = (const float*)d_in[14];
    const float* l0_bih  = (const float*)d_in[15];
    const float* l0_bhh  = (const float*)d_in[16];
    const float* l1_Wih  = (const float*)d_in[17];
    const float* l1_Whh  = (const float*)d_in[18];
    const float* l1_bih  = (const float*)d_in[19];
    const float* l1_bhh  = (const float*)d_in[20];
    const float* fc_W    = (const float*)d_in[21];
    const float* fc_b    = (const float*)d_in[22];

    float* ws = (float*)d_ws;
    float* g0    = ws;                    // [M][N][64]
    float* g1    = ws + 4194304;          // [M][N][64]
    float* seq   = ws + 8388608;          // [B*N][T][64]
    float* xg    = ws + 12582912;         // [2][65536][256]
    float* fin   = ws + 46137344;         // [NSEQ][128]
    float* o1    = ws;                    // reuse g0+g1 [NSEQ][T][128]

    // Wih' (bf16 hi/lo, frag-ordered) OVERLAPS fin: lifetimes disjoint
    __bf16* w0h = (__bf16*)(ws + 46137344);
    __bf16* w0l = w0h + 2 * 64 * 256;
    __bf16* w1h = w0l + 2 * 64 * 256;
    __bf16* w1l = w1h + 2 * 128 * 256;

    // Whh' frags live in the seq region (dead after xg_mfma<64>)
    __bf16* whhf = (__bf16*)seq;          // [2 layers][hi 32768 | lo 32768]

    wcvt_kernel<64><<<128, 256, 0, stream>>>(l0_Wih, w0h, w0l);
    wcvt_kernel<128><<<256, 256, 0, stream>>>(l1_Wih, w1h, w1l);
    gat_kernel<32><<<MM, 256, 0, stream>>>(x, adj, gat0_W, gat0_a, gat0_g, gat0_b, g0);
    gat_kernel<64><<<MM, 256, 0, stream>>>(g0, adj, gat1_W, gat1_a, gat1_g, gat1_b, g1);
    combine_kernel<<<(BB*SS*NN)/4, 256, 0, stream>>>(x, g1, res_W, res_b, alpha_g, seq);
    xg_mfma_kernel<64><<<2048, 256, 0, stream>>>(seq, w0h, w0l, l0_bih, l0_bhh, xg);
    whhcvt_kernel<<<256, 256, 0, stream>>>(l0_Whh, l1_Whh, whhf);
    lstm_rec_kernel<<<512, 256, 0, stream>>>(xg, whhf, o1, 1);
    xg_mfma_kernel<128><<<2048, 256, 0, stream>>>(o1, w1h, w1l, l1_bih, l1_bhh, xg);
    lstm_rec_kernel<<<512, 256, 0, stream>>>(xg, whhf + 65536, fin, 0);
    fc_kernel<<<NSEQ/256, 256, 0, stream>>>(fin, fc_W, fc_b, (float*)d_out);
}

// Round 15
// 442.664 us; speedup vs baseline: 1.3123x; 1.0630x over previous
//
#include <hip/hip_runtime.h>
#include <math.h>

// Problem constants
#define BB 4
#define SS 64
#define NN 256
#define FF 32
#define HH 64
#define MM (BB*SS)      // 256 graphs
#define NSEQ (BB*NN)    // 1024 sequences
#define TT SS           // 64 timesteps
#define MROWS (NSEQ*TT) // 65536 GEMM rows

// fast activations: v_rcp_f32 (~1ulp) instead of IEEE divide
__device__ __forceinline__ float fast_rcp(float x) { return __builtin_amdgcn_rcpf(x); }
__device__ __forceinline__ float sigmoid_f(float x) { return fast_rcp(1.0f + __expf(-x)); }
__device__ __forceinline__ float tanh_f(float x) {
    float t = __expf(-2.0f * fabsf(x));
    float r = (1.0f - t) * fast_rcp(1.0f + t);
    return copysignf(r, x);
}

// LDS-only barrier: waits ONLY lgkmcnt (LDS) before s_barrier, leaving global
// prefetch loads / stores IN FLIGHT across the barrier.
// sched_barrier(0) pins post-barrier ds_reads (guide rule #18).
__device__ __forceinline__ void lds_barrier() {
    asm volatile("s_waitcnt lgkmcnt(0)" ::: "memory");
    __builtin_amdgcn_s_barrier();
    __builtin_amdgcn_sched_barrier(0);
}

// ---- bf16 split helpers (RTNE hi, hi+lo captures ~17 mantissa bits) ----
typedef __bf16 bf16x8 __attribute__((ext_vector_type(8)));
typedef float  f32x4  __attribute__((ext_vector_type(4)));

__device__ __forceinline__ __bf16 bfh(float x) {
    unsigned u = __float_as_uint(x);
    unsigned r = (u + 0x7FFFu + ((u >> 16) & 1u)) >> 16;
    return __builtin_bit_cast(__bf16, (unsigned short)r);
}
__device__ __forceinline__ float bf2f(__bf16 b) {
    unsigned u = ((unsigned)__builtin_bit_cast(unsigned short, b)) << 16;
    return __uint_as_float(u);
}

// ---------------------------------------------------------------------------
// GAT layer v4 = v3 MFMA aggregation at 512 threads (8 waves).
// r14 counters: MfmaUtil 3%, VALU 27%, Occupancy 10.8% (1 wave/SIMD, LDS
// 113.7KB) -> latency-bound. 8 waves = 2 waves/SIMD doubles latency hiding
// with the SAME LDS footprint and SAME verified MFMA layout.
// Work split: phase A row-groups mod 8; s1/s2 + F-convert + make_p by
// (row = tid>>1, half = tid&1), halves combined via shfl_xor(1) (same wave).
// MFMA: wave owns a 32-row slab (acc[2][4]).
// ---------------------------------------------------------------------------
template<int FIN>
__global__ __launch_bounds__(512) void gat_kernel(
    const float* __restrict__ xin,   // [M][N][FIN]
    const float* __restrict__ adj,   // [M][N][N]
    const float* __restrict__ W,     // [FIN][64]
    const float* __restrict__ a,     // [128]
    const float* __restrict__ gamma_, const float* __restrict__ beta_,
    float* __restrict__ gout)        // [M][N][64]
{
    __shared__ __align__(16) float u_f32[256 * 68];     // 69632 B, reused as F
    __shared__ __align__(16) __bf16 p_hi[256 * 40];     // 20480 B
    __shared__ __align__(16) __bf16 p_lo[256 * 40];
    __shared__ float s1s[256], s2s[256], srow[256];

    __bf16* F_hi = (__bf16*)u_f32;          // [64][264] bf16 (33792 B)
    __bf16* F_lo = F_hi + 64 * 264;         // (+33792 B <= 69632) OK

    const int m    = blockIdx.x;
    const int tid  = threadIdx.x;
    const int lane = tid & 63;
    const int wv   = tid >> 6;        // 0..7
    const int nl   = lane & 15;
    const int lq   = lane >> 4;
    const int row2 = tid >> 1;        // 0..255 (split-half row)
    const int half = tid & 1;

    // ---- Phase A: h = x @ W -> U (fp32, stride 68); rows i == wv (mod 8) ----
    {
        const int c = tid & 63;
        float wreg[FIN];
#pragma unroll
        for (int f = 0; f < FIN; ++f) wreg[f] = W[f * 64 + c];
        const float* xm = xin + (size_t)m * NN * FIN;
        for (int i0 = 0; i0 < 32; ++i0) {
            int i = (i0 << 3) | wv;
            float acc = 0.0f;
#pragma unroll
            for (int f4 = 0; f4 < FIN / 4; ++f4) {
                float4 xv = *(const float4*)&xm[i * FIN + f4 * 4];
                acc += xv.x * wreg[f4*4] + xv.y * wreg[f4*4+1]
                     + xv.z * wreg[f4*4+2] + xv.w * wreg[f4*4+3];
            }
            u_f32[i * 68 + c] = acc;
        }
    }
    __syncthreads();

    // ---- s1/s2 (half-row per thread, shfl-combined) + keep half-row regs ----
    float hr[32];
    {
        const float* hp = &u_f32[row2 * 68 + half * 32];
        float acc1 = 0.0f, acc2 = 0.0f;
#pragma unroll
        for (int c4 = 0; c4 < 8; ++c4) {
            float4 hv = *(const float4*)&hp[c4 * 4];
            hr[c4*4+0] = hv.x; hr[c4*4+1] = hv.y; hr[c4*4+2] = hv.z; hr[c4*4+3] = hv.w;
            float4 av1 = *(const float4*)&a[half * 32 + c4 * 4];
            float4 av2 = *(const float4*)&a[64 + half * 32 + c4 * 4];
            acc1 += hv.x * av1.x + hv.y * av1.y + hv.z * av1.z + hv.w * av1.w;
            acc2 += hv.x * av2.x + hv.y * av2.y + hv.z * av2.z + hv.w * av2.w;
        }
        acc1 += __shfl_xor(acc1, 1);
        acc2 += __shfl_xor(acc2, 1);
        if (half == 0) { s1s[row2] = acc1; s2s[row2] = acc2; }
    }
    __syncthreads();                       // ALL U reads done before overwrite
    {
#pragma unroll
        for (int cc = 0; cc < 32; ++cc) {
            int c = half * 32 + cc;
            __bf16 hh = bfh(hr[cc]);
            F_hi[c * 264 + row2] = hh;
            F_lo[c * 264 + row2] = bfh(hr[cc] - bf2f(hh));
        }
    }

    // ---- chunk loop: p staging (16 k per thread) + MFMA (32-row slabs) ----
    const float* adjr = adj + ((size_t)m * NN + row2) * NN + half * 16;
    const float s1v = s1s[row2];
    float srow_acc = 0.0f;

    f32x4 acc[2][4];
#pragma unroll
    for (int mt = 0; mt < 2; ++mt)
#pragma unroll
        for (int nt = 0; nt < 4; ++nt)
            acc[mt][nt] = (f32x4){0.0f, 0.0f, 0.0f, 0.0f};

    float4 adjreg[4];
#pragma unroll
    for (int q = 0; q < 4; ++q) adjreg[q] = *(const float4*)&adjr[q * 4];

    for (int ch = 0; ch < 8; ++ch) {
        // make_p: 16 unnormalized attention weights (this thread's half)
        {
            float pv[16];
#pragma unroll
            for (int q = 0; q < 4; ++q) {
                float4 av = adjreg[q];
                float4 sv = *(const float4*)&s2s[ch * 32 + half * 16 + q * 4];
                float e0 = s1v + sv.x, e1 = s1v + sv.y, e2 = s1v + sv.z, e3 = s1v + sv.w;
                e0 = (e0 > 0.0f) ? e0 : 0.2f * e0;
                e1 = (e1 > 0.0f) ? e1 : 0.2f * e1;
                e2 = (e2 > 0.0f) ? e2 : 0.2f * e2;
                e3 = (e3 > 0.0f) ? e3 : 0.2f * e3;
                float p0 = (av.x > 0.0f) ? __expf(e0) : 0.0f;
                float p1 = (av.y > 0.0f) ? __expf(e1) : 0.0f;
                float p2 = (av.z > 0.0f) ? __expf(e2) : 0.0f;
                float p3 = (av.w > 0.0f) ? __expf(e3) : 0.0f;
                srow_acc += (p0 + p1) + (p2 + p3);
                pv[q*4+0] = p0; pv[q*4+1] = p1; pv[q*4+2] = p2; pv[q*4+3] = p3;
            }
#pragma unroll
            for (int b = 0; b < 2; ++b) {
                bf16x8 h8, l8;
#pragma unroll
                for (int j = 0; j < 8; ++j) {
                    __bf16 hh = bfh(pv[b*8+j]);
                    h8[j] = hh;
                    l8[j] = bfh(pv[b*8+j] - bf2f(hh));
                }
                *(bf16x8*)&p_hi[row2 * 40 + half * 16 + b * 8] = h8;
                *(bf16x8*)&p_lo[row2 * 40 + half * 16 + b * 8] = l8;
            }
        }
        if (ch < 7) {                     // prefetch next adj chunk (in flight)
#pragma unroll
            for (int q = 0; q < 4; ++q)
                adjreg[q] = *(const float4*)&adjr[(ch + 1) * 32 + q * 4];
        }
        lds_barrier();                    // p (and F, first iter) visible

        // MFMA: wave wv owns rows [wv*32, wv*32+32)
        bf16x8 pah[2], pal[2], fbh[4], fbl[4];
#pragma unroll
        for (int mt = 0; mt < 2; ++mt) {
            int row = wv * 32 + mt * 16 + nl;
            pah[mt] = *(const bf16x8*)&p_hi[row * 40 + lq * 8];
            pal[mt] = *(const bf16x8*)&p_lo[row * 40 + lq * 8];
        }
#pragma unroll
        for (int nt = 0; nt < 4; ++nt) {
            int fo = (nt * 16 + nl) * 264 + ch * 32 + lq * 8;
            fbh[nt] = *(const bf16x8*)&F_hi[fo];
            fbl[nt] = *(const bf16x8*)&F_lo[fo];
        }
#pragma unroll
        for (int mt = 0; mt < 2; ++mt)
#pragma unroll
            for (int nt = 0; nt < 4; ++nt)
                acc[mt][nt] = __builtin_amdgcn_mfma_f32_16x16x32_bf16(
                    pah[mt], fbh[nt], acc[mt][nt], 0, 0, 0);
#pragma unroll
        for (int mt = 0; mt < 2; ++mt)
#pragma unroll
            for (int nt = 0; nt < 4; ++nt)
                acc[mt][nt] = __builtin_amdgcn_mfma_f32_16x16x32_bf16(
                    pal[mt], fbh[nt], acc[mt][nt], 0, 0, 0);
#pragma unroll
        for (int mt = 0; mt < 2; ++mt)
#pragma unroll
            for (int nt = 0; nt < 4; ++nt)
                acc[mt][nt] = __builtin_amdgcn_mfma_f32_16x16x32_bf16(
                    pah[mt], fbl[nt], acc[mt][nt], 0, 0, 0);

        lds_barrier();                    // MFMA reads done before p overwrite
    }

    {
        float sr = srow_acc + __shfl_xor(srow_acc, 1);
        if (half == 0) srow[row2] = sr;
    }
    __syncthreads();

    // ---- epilogue: normalize, LN over 64 cols (shfl over nl bits), ELU ----
    float gm[4], bt[4];
#pragma unroll
    for (int nt = 0; nt < 4; ++nt) {
        gm[nt] = gamma_[nt * 16 + nl];
        bt[nt] = beta_[nt * 16 + nl];
    }
#pragma unroll
    for (int mt = 0; mt < 2; ++mt) {
#pragma unroll
        for (int r = 0; r < 4; ++r) {
            int row = wv * 32 + mt * 16 + lq * 4 + r;
            float rinv = fast_rcp(srow[row]);
            float v[4];
            float sm = 0.0f, sq = 0.0f;
#pragma unroll
            for (int nt = 0; nt < 4; ++nt) {
                v[nt] = acc[mt][nt][r] * rinv;
                sm += v[nt]; sq += v[nt] * v[nt];
            }
#pragma unroll
            for (int off = 1; off < 16; off <<= 1) {
                sm += __shfl_xor(sm, off);
                sq += __shfl_xor(sq, off);
            }
            float mu  = sm * (1.0f / 64.0f);
            float var = sq * (1.0f / 64.0f) - mu * mu;
            float rs  = rsqrtf(var + 1e-5f);
            float* gp = &gout[((size_t)m * NN + row) * 64];
#pragma unroll
            for (int nt = 0; nt < 4; ++nt) {
                float hn = (v[nt] - mu) * rs * gm[nt] + bt[nt];
                gp[nt * 16 + nl] = (hn > 0.0f) ? hn : (__expf(hn) - 1.0f);
            }
        }
    }
}

// ---------------------------------------------------------------------------
// residual + gate*g, reshaped to sequence layout [B*N][T][H] (unchanged)
// ---------------------------------------------------------------------------
__global__ __launch_bounds__(256) void combine_kernel(
    const float* __restrict__ x,      // [B*S*N][32]
    const float* __restrict__ g1,     // [B*S*N][64]
    const float* __restrict__ res_W,  // [32][64]
    const float* __restrict__ res_b,  // [64]
    const float* __restrict__ alpha_p,
    float* __restrict__ seqout)       // [B*N][T][64]
{
    int row = blockIdx.x * 4 + (threadIdx.x >> 6);
    int h = threadIdx.x & 63;
    int mg = row >> 8, n = row & 255;
    int b = mg >> 6, s = mg & 63;
    const float* xr = x + (size_t)row * 32;
    float acc = res_b[h];
#pragma unroll
    for (int f4 = 0; f4 < 8; ++f4) {
        float4 xv = *(const float4*)&xr[f4 * 4];
        acc += xv.x * res_W[(f4*4    ) * 64 + h] + xv.y * res_W[(f4*4 + 1) * 64 + h]
             + xv.z * res_W[(f4*4 + 2) * 64 + h] + xv.w * res_W[(f4*4 + 3) * 64 + h];
    }
    float alpha = fminf(fmaxf(alpha_p[0], 0.0f), 1.0f);
    acc += alpha * g1[(size_t)row * 64 + h];
    seqout[(((size_t)(b * NN + n)) * TT + s) * 64 + h] = acc;
}

// ---------------------------------------------------------------------------
// W pre-convert: Wih[2][K][256] fp32 -> fragment-ordered bf16 hi/lo.
// ---------------------------------------------------------------------------
template<int K>
__global__ __launch_bounds__(256) void wcvt_kernel(
    const float* __restrict__ Wih, __bf16* __restrict__ Wh, __bf16* __restrict__ Wl)
{
    constexpr int NKC = K / 32;
    int idx = blockIdx.x * 256 + threadIdx.x;
    int j   = idx & 7;
    int nl  = (idx >> 3) & 15;
    int g   = (idx >> 7) & 3;
    int ng  = (idx >> 9) & 15;
    int rest = idx >> 13;                 // dir*NKC + kc
    int kc  = rest & (NKC - 1);
    int dir = rest / NKC;
    int k = kc * 32 + g * 8 + j;
    int n = ng * 16 + nl;
    float x = Wih[((size_t)dir * K + k) * 256 + n];
    __bf16 h = bfh(x);
    Wh[idx] = h;
    Wl[idx] = bfh(x - bf2f(h));
}

// ---------------------------------------------------------------------------
// Whh pre-convert (both layers, one launch): same frag layout as wcvt<64>.
// ---------------------------------------------------------------------------
__global__ __launch_bounds__(256) void whhcvt_kernel(
    const float* __restrict__ W0, const float* __restrict__ W1,
    __bf16* __restrict__ outw)
{
    int idx = blockIdx.x * 256 + threadIdx.x;   // 0..65535
    int lay = idx >> 15;
    int r   = idx & 32767;
    int j   = r & 7;
    int nl  = (r >> 3) & 15;
    int g   = (r >> 7) & 3;
    int ng  = (r >> 9) & 15;
    int rest = r >> 13;                  // dir*2 + kc
    int kc  = rest & 1;
    int dir = rest >> 1;
    int k = kc * 32 + g * 8 + j;
    int n = ng * 16 + nl;
    const float* W = lay ? W1 : W0;
    float x = W[((size_t)dir * 64 + k) * 256 + n];
    __bf16 h = bfh(x);
    outw[lay * 65536 + r]         = h;
    outw[lay * 65536 + 32768 + r] = bfh(x - bf2f(h));
}

// ---------------------------------------------------------------------------
// xg GEMM via split-bf16 MFMA — gate-grouped wave columns, coalesced float4
// epilogue into [k][gate] layout, lds_barrier pipeline (unchanged from r14).
// ---------------------------------------------------------------------------
template<int K>
__global__ __launch_bounds__(256, 2) void xg_mfma_kernel(
    const float* __restrict__ A,       // [MROWS][K]
    const __bf16* __restrict__ Wh,     // frag-ordered
    const __bf16* __restrict__ Wl,
    const float* __restrict__ bih,     // [2][256]
    const float* __restrict__ bhh,     // [2][256]
    float* __restrict__ xg)            // [2][MROWS][64k][4g]
{
    constexpr int NKC = K / 32;
    __shared__ __bf16 a_h[2][128 * 32];
    __shared__ __bf16 a_l[2][128 * 32];

    const int tid  = threadIdx.x;
    const int lane = tid & 63;
    const int w    = tid >> 6;
    const int wr   = w >> 1, wc = w & 1;

    int bid = blockIdx.x;
    int wg  = (bid >> 3) | ((bid & 7) << 8);
    int cd  = wg & 3;
    int m0  = (wg >> 2) * 128;
    int dir = cd >> 1;
    const int kq = (cd & 1) * 2 + wc;    // wave's 16-k group (0..3)

    f32x4 acc[4][4];
#pragma unroll
    for (int mi = 0; mi < 4; ++mi)
#pragma unroll
        for (int ni = 0; ni < 4; ++ni)
            acc[mi][ni] = (f32x4){0.0f, 0.0f, 0.0f, 0.0f};

    const int srow = tid >> 1;
    const int g0   = (tid & 1) * 2;
    const float* abase = A + (size_t)(m0 + srow) * K + (tid & 1) * 16;
    const int soff0 = srow * 32 + (( g0      ^ (srow & 3)) * 8);
    const int soff1 = srow * 32 + (((g0 + 1) ^ (srow & 3)) * 8);

    int aoff[4];
#pragma unroll
    for (int mi = 0; mi < 4; ++mi)
        aoff[mi] = (wr * 64 + mi * 16 + (lane & 15)) * 32
                 + (((lane >> 4) ^ (lane & 3)) * 8);

    auto cvtstore = [&](const float* f, int buf) {
        bf16x8 h0, h1, l0, l1;
#pragma unroll
        for (int i = 0; i < 8; ++i) {
            __bf16 ha = bfh(f[i]);
            __bf16 hb = bfh(f[8 + i]);
            h0[i] = ha; l0[i] = bfh(f[i]     - bf2f(ha));
            h1[i] = hb; l1[i] = bfh(f[8 + i] - bf2f(hb));
        }
        *(bf16x8*)&a_h[buf][soff0] = h0;
        *(bf16x8*)&a_h[buf][soff1] = h1;
        *(bf16x8*)&a_l[buf][soff0] = l0;
        *(bf16x8*)&a_l[buf][soff1] = l1;
    };

    {
        float f[16];
#pragma unroll
        for (int i = 0; i < 4; ++i) {
            float4 v = *(const float4*)(abase + i * 4);
            f[i*4+0] = v.x; f[i*4+1] = v.y; f[i*4+2] = v.z; f[i*4+3] = v.w;
        }
        cvtstore(f, 0);
    }
    lds_barrier();

    int buf = 0;
    for (int kc = 0; kc < NKC; ++kc) {
        float f[16];
        if (kc + 1 < NKC) {
#pragma unroll
            for (int i = 0; i < 4; ++i) {
                float4 v = *(const float4*)(abase + (kc + 1) * 32 + i * 4);
                f[i*4+0] = v.x; f[i*4+1] = v.y; f[i*4+2] = v.z; f[i*4+3] = v.w;
            }
        }
        bf16x8 bh[4], bl[4];
#pragma unroll
        for (int ni = 0; ni < 4; ++ni) {   // ni = gate
            size_t fb = ((size_t)((dir * NKC + kc) * 16 + ni * 4 + kq)) * 512 + lane * 8;
            bh[ni] = *(const bf16x8*)(Wh + fb);
            bl[ni] = *(const bf16x8*)(Wl + fb);
        }
        bf16x8 ah[4], al[4];
#pragma unroll
        for (int mi = 0; mi < 4; ++mi) {
            ah[mi] = *(const bf16x8*)&a_h[buf][aoff[mi]];
            al[mi] = *(const bf16x8*)&a_l[buf][aoff[mi]];
        }
#pragma unroll
        for (int mi = 0; mi < 4; ++mi)
#pragma unroll
            for (int ni = 0; ni < 4; ++ni)
                acc[mi][ni] = __builtin_amdgcn_mfma_f32_16x16x32_bf16(
                    ah[mi], bh[ni], acc[mi][ni], 0, 0, 0);
#pragma unroll
        for (int mi = 0; mi < 4; ++mi)
#pragma unroll
            for (int ni = 0; ni < 4; ++ni)
                acc[mi][ni] = __builtin_amdgcn_mfma_f32_16x16x32_bf16(
                    al[mi], bh[ni], acc[mi][ni], 0, 0, 0);
#pragma unroll
        for (int mi = 0; mi < 4; ++mi)
#pragma unroll
            for (int ni = 0; ni < 4; ++ni)
                acc[mi][ni] = __builtin_amdgcn_mfma_f32_16x16x32_bf16(
                    ah[mi], bl[ni], acc[mi][ni], 0, 0, 0);

        if (kc + 1 < NKC) cvtstore(f, buf ^ 1);
        lds_barrier();
        buf ^= 1;
    }

    // epilogue: assemble i,f,g,o per (row,k) into one coalesced float4
    const int kcol = kq * 16 + (lane & 15);
    float bias4[4];
#pragma unroll
    for (int g = 0; g < 4; ++g)
        bias4[g] = bih[dir * 256 + g * 64 + kcol] + bhh[dir * 256 + g * 64 + kcol];
#pragma unroll
    for (int mi = 0; mi < 4; ++mi) {
        int mrow = m0 + wr * 64 + mi * 16 + ((lane >> 4) << 2);
#pragma unroll
        for (int r = 0; r < 4; ++r) {
            float4 v = make_float4(acc[mi][0][r] + bias4[0], acc[mi][1][r] + bias4[1],
                                   acc[mi][2][r] + bias4[2], acc[mi][3][r] + bias4[3]);
            *(float4*)&xg[((size_t)dir * MROWS + mrow + r) * 256 + kcol * 4] = v;
        }
    }
}

// ---------------------------------------------------------------------------
// LSTM recurrence v11 (unchanged from r14): G=4, grid 512, lds_barrier,
// ping-pong prefetch, all-64-lane cell phase via shfl redistribution.
// ---------------------------------------------------------------------------
__global__ __launch_bounds__(256, 2) void lstm_rec_kernel(
    const float* __restrict__ xg,     // [2][NSEQ][T][64k][4g]
    const __bf16* __restrict__ whhf,  // [hi 32768 | lo 32768] frag-ordered
    float* __restrict__ out,
    int write_all)
{
    const int tid  = threadIdx.x;
    const int wv   = tid >> 6;        // wave 0..3 = k-slice
    const int lane = tid & 63;
    const int nl   = lane & 15;
    const int lq   = lane >> 4;       // = this lane's seq (cell phase)

    const int bid  = blockIdx.x;      // grid 512
    const int dir  = bid & 1;
    const int seq0 = (bid >> 1) * 4;  // 4 seqs per block

    // B fragments: Whh' hi/lo, held in VGPRs for the whole kernel
    const __bf16* wh = whhf;
    const __bf16* wl = whhf + 32768;
    bf16x8 bh[2][4], bl[2][4];
#pragma unroll
    for (int kc = 0; kc < 2; ++kc)
#pragma unroll
        for (int g = 0; g < 4; ++g) {
            size_t fb = ((size_t)((dir * 2 + kc) * 16 + g * 4 + wv)) * 512 + lane * 8;
            bh[kc][g] = *(const bf16x8*)(wh + fb);
            bl[kc][g] = *(const bf16x8*)(wl + fb);
        }

    // h broadcast buffers: [parity][s(16)][k(64)] bf16, XOR-swizzled on k>>3
    __shared__ __align__(16) __bf16 h_hi[2048];
    __shared__ __align__(16) __bf16 h_lo[2048];
    {
        uint4 z = {0, 0, 0, 0};
        *(uint4*)&h_hi[tid * 8] = z;
        *(uint4*)&h_lo[tid * 8] = z;
    }

    const int k   = wv * 16 + nl;     // this lane's hidden index (cell phase)
    const int g8k = k >> 3;

    float c = 0.0f;                   // ONE cell per lane
    float4 xa = {}, xb = {};

    // stepping pointers: lane loads the float4 (all 4 gates) for (seq0+lq, k)
    const float* pxg = xg + (((size_t)dir * NSEQ + seq0 + lq) * TT
                             + (dir ? (TT - 1) : 0)) * 256 + k * 4;
    const int dstep = dir ? -256 : 256;
    float* pout = out + (((size_t)(seq0 + lq)) * TT + (dir ? (TT - 1) : 0)) * 128
                + dir * 64 + k;
    const int ostep = dir ? -128 : 128;

    auto load_xg = [&](float4& d) {
        d = *(const float4*)pxg;
        pxg += dstep;
    };

    int buf = 0;
    auto step_body = [&](int step, float4& xcur, float4& xnext, bool pre) {
        // A fragments: h(step) from LDS buf
        const int aof0 = buf * 1024 + nl * 64 + (((0 + lq) ^ (nl & 7)) * 8);
        const int aof1 = buf * 1024 + nl * 64 + (((4 + lq) ^ (nl & 7)) * 8);
        bf16x8 ah0 = *(const bf16x8*)&h_hi[aof0];
        bf16x8 ah1 = *(const bf16x8*)&h_hi[aof1];
        bf16x8 al0 = *(const bf16x8*)&h_lo[aof0];
        bf16x8 al1 = *(const bf16x8*)&h_lo[aof1];

        if (pre) load_xg(xnext);          // stays in flight a FULL step

        f32x4 acc[4];
#pragma unroll
        for (int g = 0; g < 4; ++g) acc[g] = (f32x4){0.0f, 0.0f, 0.0f, 0.0f};
#pragma unroll
        for (int g = 0; g < 4; ++g)
            acc[g] = __builtin_amdgcn_mfma_f32_16x16x32_bf16(ah0, bh[0][g], acc[g], 0, 0, 0);
#pragma unroll
        for (int g = 0; g < 4; ++g)
            acc[g] = __builtin_amdgcn_mfma_f32_16x16x32_bf16(ah1, bh[1][g], acc[g], 0, 0, 0);
#pragma unroll
        for (int g = 0; g < 4; ++g)
            acc[g] = __builtin_amdgcn_mfma_f32_16x16x32_bf16(al0, bh[0][g], acc[g], 0, 0, 0);
#pragma unroll
        for (int g = 0; g < 4; ++g)
            acc[g] = __builtin_amdgcn_mfma_f32_16x16x32_bf16(al1, bh[1][g], acc[g], 0, 0, 0);
#pragma unroll
        for (int g = 0; g < 4; ++g)
            acc[g] = __builtin_amdgcn_mfma_f32_16x16x32_bf16(ah0, bl[0][g], acc[g], 0, 0, 0);
#pragma unroll
        for (int g = 0; g < 4; ++g)
            acc[g] = __builtin_amdgcn_mfma_f32_16x16x32_bf16(ah1, bl[1][g], acc[g], 0, 0, 0);

        // redistribute: lane (lq,nl) takes acc[g][r=lq] from lane nl
        float pre4[4];
#pragma unroll
        for (int g = 0; g < 4; ++g) {
            float b0 = __shfl(acc[g][0], nl);
            float b1 = __shfl(acc[g][1], nl);
            float b2 = __shfl(acc[g][2], nl);
            float b3 = __shfl(acc[g][3], nl);
            float v01 = (lq & 1) ? b1 : b0;
            float v23 = (lq & 1) ? b3 : b2;
            pre4[g] = (lq & 2) ? v23 : v01;
        }

        // cell update: ONE cell per lane (s = lq, k)
        float iv = sigmoid_f(pre4[0] + xcur.x);
        float fv = sigmoid_f(pre4[1] + xcur.y);
        float gv = tanh_f  (pre4[2] + xcur.z);
        float ov = sigmoid_f(pre4[3] + xcur.w);
        c = fv * c + iv * gv;
        float h = ov * tanh_f(c);
        int off = (buf ^ 1) * 1024 + lq * 64 + ((g8k ^ lq) * 8) + (k & 7);
        __bf16 hh = bfh(h);
        h_hi[off] = hh;
        h_lo[off] = bfh(h - bf2f(hh));
        if (write_all)
            pout[0] = h;
        else if (step == TT - 1)
            out[(size_t)(seq0 + lq) * 128 + dir * 64 + k] = h;
        pout += ostep;
        lds_barrier();
        buf ^= 1;
    };

    load_xg(xa);                           // t=0
    lds_barrier();

    for (int step = 0; step < TT; step += 2) {
        step_body(step,     xa, xb, true);             // consume xa, fetch t+1
        step_body(step + 1, xb, xa, step + 2 < TT);    // consume xb, fetch t+2
    }
}

// ---------------------------------------------------------------------------
__global__ __launch_bounds__(256) void fc_kernel(
    const float* __restrict__ fin,   // [NSEQ][128]
    const float* __restrict__ fc_W,  // [128]
    const float* __restrict__ fc_b,  // [1]
    float* __restrict__ outp)        // [NSEQ]
{
    int s = blockIdx.x * 256 + threadIdx.x;
    const float* fr = fin + (size_t)s * 128;
    float acc = fc_b[0];
#pragma unroll
    for (int k4 = 0; k4 < 32; ++k4) {
        float4 fv = *(const float4*)&fr[k4 * 4];
        float4 wv2 = *(const float4*)&fc_W[k4 * 4];
        acc += fv.x * wv2.x + fv.y * wv2.y + fv.z * wv2.z + fv.w * wv2.w;
    }
    outp[s] = acc;
}

// ---------------------------------------------------------------------------
extern "C" void kernel_launch(void* const* d_in, const int* in_sizes, int n_in,
                              void* d_out, int out_size, void* d_ws, size_t ws_size,
                              hipStream_t stream) {
    const float* x       = (const float*)d_in[0];
    const float* adj     = (const float*)d_in[1];
    const float* gat0_W  = (const float*)d_in[2];
    const float* gat0_a  = (const float*)d_in[3];
    const float* gat0_g  = (const float*)d_in[4];
    const float* gat0_b  = (const float*)d_in[5];
    const float* gat1_W  = (const float*)d_in[6];
    const float* gat1_a  = (const float*)d_in[7];
    const float* gat1_g  = (const float*)d_in[8];
    const float* gat1_b  = (const float*)d_in[9];
    const float* res_W   = (const float*)d_in[10];
    const float* res_b   = (const float*)d_in[11];
    const float* alpha_g = (const float*)d_in[12];
    const float* l0_Wih  = (const float*)d_in[13];
    const float* l0_Whh  = (const float*)d_in[14];
    const float* l0_bih  = (const float*)d_in[15];
    const float* l0_bhh  = (const float*)d_in[16];
    const float* l1_Wih  = (const float*)d_in[17];
    const float* l1_Whh  = (const float*)d_in[18];
    const float* l1_bih  = (const float*)d_in[19];
    const float* l1_bhh  = (const float*)d_in[20];
    const float* fc_W    = (const float*)d_in[21];
    const float* fc_b    = (const float*)d_in[22];

    float* ws = (float*)d_ws;
    float* g0    = ws;                    // [M][N][64]
    float* g1    = ws + 4194304;          // [M][N][64]
    float* seq   = ws + 8388608;          // [B*N][T][64]
    float* xg    = ws + 12582912;         // [2][65536][256]
    float* fin   = ws + 46137344;         // [NSEQ][128]
    float* o1    = ws;                    // reuse g0+g1 [NSEQ][T][128]

    // Wih' (bf16 hi/lo, frag-ordered) OVERLAPS fin: lifetimes disjoint
    __bf16* w0h = (__bf16*)(ws + 46137344);
    __bf16* w0l = w0h + 2 * 64 * 256;
    __bf16* w1h = w0l + 2 * 64 * 256;
    __bf16* w1l = w1h + 2 * 128 * 256;

    // Whh' frags live in the seq region (dead after xg_mfma<64>)
    __bf16* whhf = (__bf16*)seq;          // [2 layers][hi 32768 | lo 32768]

    wcvt_kernel<64><<<128, 256, 0, stream>>>(l0_Wih, w0h, w0l);
    wcvt_kernel<128><<<256, 256, 0, stream>>>(l1_Wih, w1h, w1l);
    gat_kernel<32><<<MM, 512, 0, stream>>>(x, adj, gat0_W, gat0_a, gat0_g, gat0_b, g0);
    gat_kernel<64><<<MM, 512, 0, stream>>>(g0, adj, gat1_W, gat1_a, gat1_g, gat1_b, g1);
    combine_kernel<<<(BB*SS*NN)/4, 256, 0, stream>>>(x, g1, res_W, res_b, alpha_g, seq);
    xg_mfma_kernel<64><<<2048, 256, 0, stream>>>(seq, w0h, w0l, l0_bih, l0_bhh, xg);
    whhcvt_kernel<<<256, 256, 0, stream>>>(l0_Whh, l1_Whh, whhf);
    lstm_rec_kernel<<<512, 256, 0, stream>>>(xg, whhf, o1, 1);
    xg_mfma_kernel<128><<<2048, 256, 0, stream>>>(o1, w1h, w1l, l1_bih, l1_bhh, xg);
    lstm_rec_kernel<<<512, 256, 0, stream>>>(xg, whhf + 65536, fin, 0);
    fc_kernel<<<NSEQ/256, 256, 0, stream>>>(fin, fc_W, fc_b, (float*)d_out);
}